// Round 7
// baseline (327.822 us; speedup 1.0000x reference)
//
#include <hip/hip_runtime.h>
#include <hip/hip_bf16.h>

// ViT attention, MFMA bf16 pipeline. B=16, N=1024, C=768, H=12, D=64.
// Round 12: gemm K-loop -> triple-buffered depth-2 pipeline with COUNTED
// vmcnt + raw s_barrier (T4). __syncthreads' implicit vmcnt(0) was draining
// the depth-1 prefetch ~650cyc early (round-6 regression); now tile ki's
// loads are issued 2 iterations ahead and the barrier waits only vmcnt(4)
// (the one younger tile in flight). One barrier per K-step. BK=32, LDS
// 48 KB (3 bufs x 2 mats x 8 KB) -> 3 blocks/CU. K=768 compile-time ->
// static vmcnt immediates, %3 buffers constant under unroll-by-3.
// Race audit: stage(ki+2) AFTER barrier (all waves' ds_reads of that buf
// completed pre-barrier, lgkmcnt-gated by their MFMAs); per-wave vmcnt(4)
// pre-barrier => all 16 tile-ki loads visible before any wave computes.
// attn: unchanged round-10/11 (74.4 us measured): S^T=K*Q^T 32x32 MFMA,
// in-register softmax (v_exp_f32, cvt_pk, permlane32_swap), setprio on
// MFMA clusters, dbuf K/V via gld16.
// MFMA 32x32x16 bf16 layouts (m74/m101):
//   A-op: lane holds A[m=lane&31][k=8*(lane>>5)+j]
//   B-op: lane holds B[k=8*(lane>>5)+j][n=lane&31]
//   C/D : reg r = D[row=(r&3)+8*(r>>2)+4*(lane>>5)][col=lane&31]
// MFMA 16x16x32 bf16 layouts (m89/m91):
//   A/B-op: lane(quad,l16) holds [m=l16][k=quad*8+j]
//   C/D   : reg r = D[row=quad*4+r][col=l16]

typedef __attribute__((ext_vector_type(8))) short short8;
typedef __attribute__((ext_vector_type(4))) float floatx4;
typedef __attribute__((ext_vector_type(16))) float floatx16;
typedef __attribute__((ext_vector_type(2))) unsigned int uint2v;

constexpr int Bsz = 16, Nseq = 1024, Cdim = 768, Hh = 12, Dd = 64;
constexpr float QSC = 0.1803368801f;       // 64^-0.5 * log2(e), folded into Q
constexpr int LDV = Bsz * Nseq;            // 16384, vt leading dim

__device__ __forceinline__ ushort f2bs(float f) {
    union { __hip_bfloat16 h; ushort u; } cv;
    cv.h = __float2bfloat16(f);
    return cv.u;
}
__device__ __forceinline__ void stF(float* p, float v) { *p = v; }
__device__ __forceinline__ void stF(ushort* p, float v) { *p = f2bs(v); }

__device__ __forceinline__ float fexp2(float x) {
#if __has_builtin(__builtin_amdgcn_exp2f)
    return __builtin_amdgcn_exp2f(x);   // raw v_exp_f32; inputs |x|<~40, safe
#else
    return exp2f(x);
#endif
}

// async 16B/lane global->LDS DMA. lds must be wave-uniform; HW adds lane*16.
__device__ __forceinline__ void gld16(void* lds, const void* g) {
    __builtin_amdgcn_global_load_lds(
        (const __attribute__((address_space(1))) unsigned int*)g,
        (__attribute__((address_space(3))) unsigned int*)lds, 16, 0, 0);
}

// fp32 -> bf16 pack: x | qkv_w | proj_w
__global__ __launch_bounds__(256) void pack_bf16(
        const float* __restrict__ x, const float* __restrict__ w1,
        const float* __restrict__ w2, ushort* __restrict__ xb,
        ushort* __restrict__ w1b, ushort* __restrict__ w2b) {
    const size_t n0 = (size_t)Bsz * Nseq * Cdim;   // 12,582,912
    const size_t n1 = (size_t)3 * Cdim * Cdim;     //  1,769,472
    size_t i = ((size_t)blockIdx.x * 256 + threadIdx.x) * 4;
    const float* src;
    ushort* dst;
    if (i < n0) { src = x; dst = xb; }
    else if (i < n0 + n1) { i -= n0; src = w1; dst = w1b; }
    else { i -= n0 + n1; src = w2; dst = w2b; }
    float4 v = *(const float4*)&src[i];
    *(ushort4*)&dst[i] = make_ushort4(f2bs(v.x), f2bs(v.y), f2bs(v.z), f2bs(v.w));
}

// C = A[M,K=768] @ Bw[N,768]^T + bias. 128x128 tile, BK=32, triple-buffered
// depth-2 prefetch, counted vmcnt + raw barrier. 256 thr, 4 waves.
// bias_row ? bias[row] : bias[col]. Cols < qsplit scaled by qscale.
template <typename TO>
__global__ __launch_bounds__(256) void gemm_nt_mfma(
        const ushort* __restrict__ A, const ushort* __restrict__ Bw,
        const float* __restrict__ bias, TO* __restrict__ C0,
        int ld0, int M, int N, int bias_row, int qsplit, float qscale) {
    constexpr int KK = 768;
    constexpr int NK = KK / 32;          // 24 K-steps
    __shared__ ushort As[3][128 * 32];   // [buf][row][k], XOR-4 swizzled
    __shared__ ushort Bs[3][128 * 32];
    const int t = threadIdx.x;
    const int lane = t & 63;
    const int w = t >> 6;
    const int quad = lane >> 4;
    const int l16 = lane & 15;
    const int m0 = blockIdx.y * 128;
    const int n0 = blockIdx.x * 128;

    const int mw = (w >> 1) * 64;
    const int nw = (w & 1) * 64;
    const int srow = lane >> 2;         // 16 rows per gld16
    const int schunk = lane & 3;        // 4x16B chunks per 64B row

    floatx4 acc[4][4];
#pragma unroll
    for (int i = 0; i < 4; ++i)
#pragma unroll
        for (int j = 0; j < 4; ++j) acc[i][j] = (floatx4)0.0f;

    // stage K-slab ki into buf ki%3: 4 gld16 per wave (2 A + 2 B)
    auto stage = [&](int ki) {
        const int k0 = ki * 32;
        const int buf = ki % 3;
#pragma unroll
        for (int i = 0; i < 2; ++i) {
            int r0 = (w * 2 + i) * 16;
            int row = r0 + srow;
            int cs = (schunk ^ (row & 3)) * 8;
            gld16(&As[buf][r0 * 32], &A[(size_t)(m0 + row) * KK + k0 + cs]);
            gld16(&Bs[buf][r0 * 32], &Bw[(size_t)(n0 + row) * KK + k0 + cs]);
        }
    };

    stage(0);
    stage(1);
#pragma unroll 3
    for (int ki = 0; ki < NK; ++ki) {
        // wait for THIS wave's tile-ki loads (4 oldest); tile ki+1 (4) may fly
        if (ki + 1 < NK)
            asm volatile("s_waitcnt vmcnt(4)" ::: "memory");
        else
            asm volatile("s_waitcnt vmcnt(0)" ::: "memory");
        __builtin_amdgcn_sched_barrier(0);
        __builtin_amdgcn_s_barrier();   // all waves: tile-ki visible, buf free
        __builtin_amdgcn_sched_barrier(0);
        if (ki + 2 < NK) stage(ki + 2);

        const ushort* Ab = As[ki % 3];
        const ushort* Bb = Bs[ki % 3];
        const int pc = (quad ^ (l16 & 3)) * 8;  // row&3 == l16&3 for reads
        short8 af[4], bfr[4];
#pragma unroll
        for (int i = 0; i < 4; ++i)
            af[i] = *(const short8*)&Ab[(mw + i * 16 + l16) * 32 + pc];
#pragma unroll
        for (int j = 0; j < 4; ++j)
            bfr[j] = *(const short8*)&Bb[(nw + j * 16 + l16) * 32 + pc];
#pragma unroll
        for (int i = 0; i < 4; ++i)
#pragma unroll
            for (int j = 0; j < 4; ++j)
                acc[i][j] = __builtin_amdgcn_mfma_f32_16x16x32_bf16(
                    af[i], bfr[j], acc[i][j], 0, 0, 0);
    }

    if (bias_row) {
        float brv[4][4];
#pragma unroll
        for (int i = 0; i < 4; ++i)
#pragma unroll
            for (int r = 0; r < 4; ++r)
                brv[i][r] = bias[m0 + mw + i * 16 + quad * 4 + r];
#pragma unroll
        for (int j = 0; j < 4; ++j) {
            int col = n0 + nw + j * 16 + l16;
#pragma unroll
            for (int i = 0; i < 4; ++i)
#pragma unroll
                for (int r = 0; r < 4; ++r) {
                    int row = m0 + mw + i * 16 + quad * 4 + r;
                    stF(&C0[(size_t)row * ld0 + col], acc[i][j][r] + brv[i][r]);
                }
        }
    } else {
#pragma unroll
        for (int j = 0; j < 4; ++j) {
            int col = n0 + nw + j * 16 + l16;
            float bc = bias[col];
            float sc = (col < qsplit) ? qscale : 1.0f;
#pragma unroll
            for (int i = 0; i < 4; ++i)
#pragma unroll
                for (int r = 0; r < 4; ++r) {
                    int row = m0 + mw + i * 16 + quad * 4 + r;
                    stF(&C0[(size_t)row * ld0 + col], (acc[i][j][r] + bc) * sc);
                }
        }
    }
}

// Flash attention, no-max softmax, S^T formulation, 32x32x16 MFMA,
// in-register P (permlane32_swap half-exchange), no P LDS.
// Block = (b,h, 128-q tile), 4 waves; wave w owns q rows w*32..w*32+31.
// KV tiles of 64, double-buffered staging.
__global__ __launch_bounds__(256, 3) void attn_mfma(
        const ushort* __restrict__ qk, const ushort* __restrict__ vt,
        ushort* __restrict__ outp) {
    __shared__ ushort Ks[2][64 * 64];   // [key][d], XOR-8 swizzled
    __shared__ ushort Vts[2][64 * 64];  // [d][key], XOR-8 swizzled

    const int t = threadIdx.x;
    const int lane = t & 63;
    const int w = t >> 6;
    const int l32 = lane & 31;
    const int hi = lane >> 5;
    const int srow = lane >> 3;
    const int schunk = lane & 7;

    // XCD swizzle: 8 q-tiles of one bh land on one XCD, consecutively.
    const int bid = blockIdx.x;
    const int qt = (bid >> 3) & 7;
    const int bh = (bid & 7) + 8 * (bid >> 6);
    const int h = bh % Hh, b = bh / Hh;

    const size_t rs = 2 * Cdim;  // 1536
    const ushort* qbase = qk + (size_t)b * Nseq * rs + h * Dd;
    const ushort* kbase = qbase + Cdim;
    // vt is [768][16384]: row = h*64+d, col = b*1024 + n
    const ushort* vbase = vt + (size_t)(h * Dd) * LDV + (size_t)b * Nseq;

    // Q fragments in registers (pre-scaled by SCALE*log2e at gemm1).
    // B-op for S^T: lane holds Q[q=l32][d=kc*16+hi*8+j]
    short8 aq[4];
    {
        int q = qt * 128 + w * 32 + l32;
#pragma unroll
        for (int kc = 0; kc < 4; ++kc)
            aq[kc] = *(const short8*)&qbase[(size_t)q * rs + kc * 16 + hi * 8];
    }

    auto stage = [&](int kt64, int buf) {
#pragma unroll
        for (int i = 0; i < 2; ++i) {
            int r0 = (w * 2 + i) * 8;
            int row = r0 + srow;
            int cs = (schunk ^ (row & 7)) * 8;
            gld16(&Ks[buf][r0 * 64], &kbase[(size_t)(kt64 * 64 + row) * rs + cs]);
            gld16(&Vts[buf][r0 * 64], &vbase[(size_t)row * LDV + kt64 * 64 + cs]);
        }
    };

    floatx16 o[2];
    o[0] = (floatx16)0.0f;
    o[1] = (floatx16)0.0f;
    float lsum = 0.f;

    stage(0, 0);
    for (int kt = 0; kt < Nseq / 64; ++kt) {
        __syncthreads();  // drains DMA for tile kt; guards buf reuse
        if (kt + 1 < Nseq / 64) stage(kt + 1, (kt + 1) & 1);
        const ushort* Kb = Ks[kt & 1];
        const ushort* Vb = Vts[kt & 1];

        // S^T = K Q^T : st[km] reg r = S^T[key=km*32+(r&3)+8*(r>>2)+4*hi][q=l32]
        floatx16 st[2];
        st[0] = (floatx16)0.0f;
        st[1] = (floatx16)0.0f;
        __builtin_amdgcn_s_setprio(1);
#pragma unroll
        for (int kc = 0; kc < 4; ++kc) {
            const int cs = ((kc * 2 + hi) ^ (l32 & 7)) * 8;
            short8 ak0 = *(const short8*)&Kb[l32 * 64 + cs];
            short8 ak1 = *(const short8*)&Kb[(32 + l32) * 64 + cs];
            st[0] = __builtin_amdgcn_mfma_f32_32x32x16_bf16(ak0, aq[kc], st[0], 0, 0, 0);
            st[1] = __builtin_amdgcn_mfma_f32_32x32x16_bf16(ak1, aq[kc], st[1], 0, 0, 0);
        }
        __builtin_amdgcn_s_setprio(0);

#pragma unroll
        for (int km = 0; km < 2; ++km) {
            // p = 2^s (Q pre-scaled by log2e); all 16 values belong to q=l32.
            // key(p[r]) = km*32 + (r&3) + 8*(r>>2) + 4*hi
            float p[16];
#pragma unroll
            for (int r = 0; r < 16; ++r) p[r] = fexp2(st[km][r]);
            lsum += (((p[0] + p[1]) + (p[2] + p[3])) +
                     ((p[4] + p[5]) + (p[6] + p[7]))) +
                    (((p[8] + p[9]) + (p[10] + p[11])) +
                     ((p[12] + p[13]) + (p[14] + p[15])));
            // pack consecutive-key pairs: c[i] = bf16(p[2i]) | bf16(p[2i+1])<<16
            uint c[8];
#pragma unroll
            for (int i = 0; i < 8; ++i) {
                union { __hip_bfloat162 h2; uint u; } cv;
                cv.h2 = __float22bfloat162_rn(make_float2(p[2 * i], p[2 * i + 1]));
                c[i] = cv.u;
            }
            // half-wave exchange: A-frag word jw holds keys (8hi+2jw, 8hi+2jw+1)
            uint wd[8];
#if __has_builtin(__builtin_amdgcn_permlane32_swap)
            uint2v r02 = __builtin_amdgcn_permlane32_swap(c[0], c[2], false, false);
            uint2v r13 = __builtin_amdgcn_permlane32_swap(c[1], c[3], false, false);
            uint2v r46 = __builtin_amdgcn_permlane32_swap(c[4], c[6], false, false);
            uint2v r57 = __builtin_amdgcn_permlane32_swap(c[5], c[7], false, false);
            wd[0] = r02.x; wd[2] = r02.y;
            wd[1] = r13.x; wd[3] = r13.y;
            wd[4] = r46.x; wd[6] = r46.y;
            wd[5] = r57.x; wd[7] = r57.y;
#else
            uint x0 = __shfl_xor(c[0], 32), x1 = __shfl_xor(c[1], 32);
            uint x2 = __shfl_xor(c[2], 32), x3 = __shfl_xor(c[3], 32);
            uint x4 = __shfl_xor(c[4], 32), x5 = __shfl_xor(c[5], 32);
            uint x6 = __shfl_xor(c[6], 32), x7 = __shfl_xor(c[7], 32);
            wd[0] = hi ? x2 : c[0]; wd[1] = hi ? x3 : c[1];
            wd[2] = hi ? c[2] : x0; wd[3] = hi ? c[3] : x1;
            wd[4] = hi ? x6 : c[4]; wd[5] = hi ? x7 : c[5];
            wd[6] = hi ? c[6] : x4; wd[7] = hi ? c[7] : x5;
#endif
            union { uint u[4]; short8 s; } af0, af1;
            af0.u[0] = wd[0]; af0.u[1] = wd[1]; af0.u[2] = wd[2]; af0.u[3] = wd[3];
            af1.u[0] = wd[4]; af1.u[1] = wd[5]; af1.u[2] = wd[6]; af1.u[3] = wd[7];

            // O[q][d] += P V : B-op = V[key][d=l32+dblk*32] from Vts[d][key]
            __builtin_amdgcn_s_setprio(1);
#pragma unroll
            for (int dblk = 0; dblk < 2; ++dblk) {
                const int row = dblk * 32 + l32;
#pragma unroll
                for (int ks = 0; ks < 2; ++ks) {
                    const int ch = ((km * 4 + ks * 2 + hi) ^ (l32 & 7)) * 8;
                    short8 bv = *(const short8*)&Vb[row * 64 + ch];
                    o[dblk] = __builtin_amdgcn_mfma_f32_32x32x16_bf16(
                        ks ? af1.s : af0.s, bv, o[dblk], 0, 0, 0);
                }
            }
            __builtin_amdgcn_s_setprio(0);
        }
    }

    // full row-sum: partner half-wave holds the other 32 keys per tile
    float lf = lsum + __shfl_xor(lsum, 32);
    float linv = __builtin_amdgcn_rcpf(lf);

    // O C-layout: col = d = l32 (+dblk*32), row = q = (r&3)+8*(r>>2)+4*hi
    const int qg0 = qt * 128 + w * 32;
#pragma unroll
    for (int r = 0; r < 16; ++r) {
        int rowq = (r & 3) + 8 * (r >> 2) + 4 * hi;
        float li = __shfl(linv, rowq);
        int q = qg0 + rowq;
#pragma unroll
        for (int dblk = 0; dblk < 2; ++dblk) {
            int d = dblk * 32 + l32;
            outp[((size_t)(b * Nseq + q)) * Cdim + h * Dd + d] =
                f2bs(o[dblk][r] * li);
        }
    }
}

extern "C" void kernel_launch(void* const* d_in, const int* in_sizes, int n_in,
                              void* d_out, int out_size, void* d_ws, size_t ws_size,
                              hipStream_t stream) {
    const float* x      = (const float*)d_in[0];
    const float* qkv_w  = (const float*)d_in[1];
    const float* qkv_b  = (const float*)d_in[2];
    const float* proj_w = (const float*)d_in[3];
    const float* proj_b = (const float*)d_in[4];
    float* out = (float*)d_out;

    const int M = Bsz * Nseq;  // 16384
    ushort* xb    = (ushort*)d_ws;                        // [16384x768]
    ushort* qk    = xb + (size_t)M * Cdim;                // [16384x1536]
    ushort* vtbuf = qk + (size_t)M * 2 * Cdim;            // [768][16384]
    ushort* wqkvb = vtbuf + (size_t)Cdim * M;             // [2304x768]
    ushort* wprjb = wqkvb + (size_t)3 * Cdim * Cdim;      // [768x768]
    ushort* attnout = xb;  // xb dead after VT-gemm

    // 0) fp32 -> bf16 pack
    pack_bf16<<<14592, 256, 0, stream>>>(x, qkv_w, proj_w, xb, wqkvb, wprjb);
    // 1a) QK GEMM: X @ Wqk^T -> qk [16384x1536]; Q cols pre-scaled by QSC
    gemm_nt_mfma<ushort><<<dim3(12, 128), 256, 0, stream>>>(
        xb, wqkvb, qkv_b, qk, 2 * Cdim, M, 2 * Cdim, 0, Cdim, QSC);
    // 1b) VT GEMM: Wv @ X^T -> vt [768][16384], bias per row, coalesced
    gemm_nt_mfma<ushort><<<dim3(128, 6), 256, 0, stream>>>(
        wqkvb + (size_t)2 * Cdim * Cdim, xb, qkv_b + 2 * Cdim, vtbuf,
        M, Cdim, M, 1, 0, 1.0f);
    // 2) attention
    attn_mfma<<<Bsz * Hh * (Nseq / 128), 256, 0, stream>>>(qk, vtbuf, attnout);
    // 3) projection -> fp32 out
    gemm_nt_mfma<float><<<dim3(6, 128), 256, 0, stream>>>(
        attnout, wprjb, proj_b, out, Cdim, M, Cdim, 0, 0, 1.0f);
}

// Round 8
// 299.677 us; speedup vs baseline: 1.0939x; 1.0939x over previous
//
#include <hip/hip_runtime.h>
#include <hip/hip_bf16.h>

// ViT attention, MFMA bf16 pipeline. B=16, N=1024, C=768, H=12, D=64.
// Round 13:
//  - gemm K-loop REVERTED to round-4's simple BK=64 / 2-barrier form (best
//    measured; rounds 10-12's pipeline surgery all regressed, replicating
//    learn_hip m131-m141: source-level pipelining of this structure loses).
//  - ADD XCD-chunked block swizzle ONLY where consecutive blocks share an
//    A-panel (QK gemm, proj gemm). Round-7 counter evidence: QK FETCH_SIZE
//    106 MB vs ideal 27 MB = ~4x A over-fetch from panels scattered across
//    8 XCD L2s. Per-XCD resident set after swizzle: B (2.25 MB) + ~1 A panel
//    < 4 MB L2. VT gemm keeps swz=0 (its B-panel readers are bids x+128k ==
//    x mod 8: already same-XCD).
//  - attn unchanged (74.4 us measured round-6/7).
// attn: S^T = K*Q^T in 32x32 MFMA, in-register softmax (raw v_exp_f32,
// cvt_pk, permlane32_swap), setprio on MFMA clusters, dbuf K/V staging.
// MFMA 32x32x16 bf16 layouts (m74/m101):
//   A-op: lane holds A[m=lane&31][k=8*(lane>>5)+j]
//   B-op: lane holds B[k=8*(lane>>5)+j][n=lane&31]
//   C/D : reg r = D[row=(r&3)+8*(r>>2)+4*(lane>>5)][col=lane&31]
// MFMA 16x16x32 bf16 layouts (m89/m91):
//   A/B-op: lane(quad,l16) holds [m=l16][k=quad*8+j]
//   C/D   : reg r = D[row=quad*4+r][col=l16]

typedef __attribute__((ext_vector_type(8))) short short8;
typedef __attribute__((ext_vector_type(4))) float floatx4;
typedef __attribute__((ext_vector_type(16))) float floatx16;
typedef __attribute__((ext_vector_type(2))) unsigned int uint2v;

constexpr int Bsz = 16, Nseq = 1024, Cdim = 768, Hh = 12, Dd = 64;
constexpr float QSC = 0.1803368801f;       // 64^-0.5 * log2(e), folded into Q
constexpr int LDV = Bsz * Nseq;            // 16384, vt leading dim

__device__ __forceinline__ ushort f2bs(float f) {
    union { __hip_bfloat16 h; ushort u; } cv;
    cv.h = __float2bfloat16(f);
    return cv.u;
}
__device__ __forceinline__ void stF(float* p, float v) { *p = v; }
__device__ __forceinline__ void stF(ushort* p, float v) { *p = f2bs(v); }

__device__ __forceinline__ float fexp2(float x) {
#if __has_builtin(__builtin_amdgcn_exp2f)
    return __builtin_amdgcn_exp2f(x);   // raw v_exp_f32; inputs |x|<~40, safe
#else
    return exp2f(x);
#endif
}

// async 16B/lane global->LDS DMA. lds must be wave-uniform; HW adds lane*16.
__device__ __forceinline__ void gld16(void* lds, const void* g) {
    __builtin_amdgcn_global_load_lds(
        (const __attribute__((address_space(1))) unsigned int*)g,
        (__attribute__((address_space(3))) unsigned int*)lds, 16, 0, 0);
}

// fp32 -> bf16 pack: x | qkv_w | proj_w
__global__ __launch_bounds__(256) void pack_bf16(
        const float* __restrict__ x, const float* __restrict__ w1,
        const float* __restrict__ w2, ushort* __restrict__ xb,
        ushort* __restrict__ w1b, ushort* __restrict__ w2b) {
    const size_t n0 = (size_t)Bsz * Nseq * Cdim;   // 12,582,912
    const size_t n1 = (size_t)3 * Cdim * Cdim;     //  1,769,472
    size_t i = ((size_t)blockIdx.x * 256 + threadIdx.x) * 4;
    const float* src;
    ushort* dst;
    if (i < n0) { src = x; dst = xb; }
    else if (i < n0 + n1) { i -= n0; src = w1; dst = w1b; }
    else { i -= n0 + n1; src = w2; dst = w2b; }
    float4 v = *(const float4*)&src[i];
    *(ushort4*)&dst[i] = make_ushort4(f2bs(v.x), f2bs(v.y), f2bs(v.z), f2bs(v.w));
}

// C = A[M,K] @ Bw[N,K]^T + bias. 128x128 tile, BK=64, 256 thr, 4 waves.
// bias_row ? bias[row] : bias[col]. Cols < qsplit scaled by qscale.
// swz: XCD-chunked block remap (use when consecutive blocks share A-panel).
template <typename TO>
__global__ __launch_bounds__(256) void gemm_nt_mfma(
        const ushort* __restrict__ A, const ushort* __restrict__ Bw,
        const float* __restrict__ bias, TO* __restrict__ C0,
        int ld0, int M, int N, int K, int bias_row, int qsplit, float qscale,
        int swz) {
    __shared__ ushort As[128 * 64];   // [row][k] unpadded, XOR-8 swizzled
    __shared__ ushort Bs[128 * 64];
    const int t = threadIdx.x;
    const int lane = t & 63;
    const int w = t >> 6;
    const int quad = lane >> 4;
    const int l16 = lane & 15;

    int bidl = blockIdx.y * gridDim.x + blockIdx.x;
    if (swz) {
        const int nwg = gridDim.x * gridDim.y;   // multiple of 8 for our grids
        const int cpx = nwg >> 3;
        bidl = (bidl & 7) * cpx + (bidl >> 3);   // bijective: nwg % 8 == 0
    }
    const int m0 = (bidl / gridDim.x) * 128;
    const int n0 = (bidl % gridDim.x) * 128;

    const int mw = (w >> 1) * 64;
    const int nw = (w & 1) * 64;
    const int srow = lane >> 3;
    const int schunk = lane & 7;

    floatx4 acc[4][4];
#pragma unroll
    for (int i = 0; i < 4; ++i)
#pragma unroll
        for (int j = 0; j < 4; ++j) acc[i][j] = (floatx4)0.0f;

    for (int k0 = 0; k0 < K; k0 += 64) {
        __syncthreads();
#pragma unroll
        for (int i = 0; i < 4; ++i) {
            int r0 = (w * 4 + i) * 8;
            int row = r0 + srow;
            int cs = (schunk ^ (row & 7)) * 8;
            gld16(&As[r0 * 64], &A[(size_t)(m0 + row) * K + k0 + cs]);
            gld16(&Bs[r0 * 64], &Bw[(size_t)(n0 + row) * K + k0 + cs]);
        }
        __syncthreads();

#pragma unroll
        for (int kk = 0; kk < 2; ++kk) {
            const int pc = ((kk * 4 + quad) ^ (l16 & 7)) * 8;
            short8 af[4], bfr[4];
#pragma unroll
            for (int i = 0; i < 4; ++i)
                af[i] = *(const short8*)&As[(mw + i * 16 + l16) * 64 + pc];
#pragma unroll
            for (int j = 0; j < 4; ++j)
                bfr[j] = *(const short8*)&Bs[(nw + j * 16 + l16) * 64 + pc];
#pragma unroll
            for (int i = 0; i < 4; ++i)
#pragma unroll
                for (int j = 0; j < 4; ++j)
                    acc[i][j] = __builtin_amdgcn_mfma_f32_16x16x32_bf16(
                        af[i], bfr[j], acc[i][j], 0, 0, 0);
        }
    }

    if (bias_row) {
        float brv[4][4];
#pragma unroll
        for (int i = 0; i < 4; ++i)
#pragma unroll
            for (int r = 0; r < 4; ++r)
                brv[i][r] = bias[m0 + mw + i * 16 + quad * 4 + r];
#pragma unroll
        for (int j = 0; j < 4; ++j) {
            int col = n0 + nw + j * 16 + l16;
#pragma unroll
            for (int i = 0; i < 4; ++i)
#pragma unroll
                for (int r = 0; r < 4; ++r) {
                    int row = m0 + mw + i * 16 + quad * 4 + r;
                    stF(&C0[(size_t)row * ld0 + col], acc[i][j][r] + brv[i][r]);
                }
        }
    } else {
#pragma unroll
        for (int j = 0; j < 4; ++j) {
            int col = n0 + nw + j * 16 + l16;
            float bc = bias[col];
            float sc = (col < qsplit) ? qscale : 1.0f;
#pragma unroll
            for (int i = 0; i < 4; ++i)
#pragma unroll
                for (int r = 0; r < 4; ++r) {
                    int row = m0 + mw + i * 16 + quad * 4 + r;
                    stF(&C0[(size_t)row * ld0 + col], (acc[i][j][r] + bc) * sc);
                }
        }
    }
}

// Flash attention, no-max softmax, S^T formulation, 32x32x16 MFMA,
// in-register P (permlane32_swap half-exchange), no P LDS.
// Block = (b,h, 128-q tile), 4 waves; wave w owns q rows w*32..w*32+31.
// KV tiles of 64, double-buffered staging.
__global__ __launch_bounds__(256, 3) void attn_mfma(
        const ushort* __restrict__ qk, const ushort* __restrict__ vt,
        ushort* __restrict__ outp) {
    __shared__ ushort Ks[2][64 * 64];   // [key][d], XOR-8 swizzled
    __shared__ ushort Vts[2][64 * 64];  // [d][key], XOR-8 swizzled

    const int t = threadIdx.x;
    const int lane = t & 63;
    const int w = t >> 6;
    const int l32 = lane & 31;
    const int hi = lane >> 5;
    const int srow = lane >> 3;
    const int schunk = lane & 7;

    // XCD swizzle: 8 q-tiles of one bh land on one XCD, consecutively.
    const int bid = blockIdx.x;
    const int qt = (bid >> 3) & 7;
    const int bh = (bid & 7) + 8 * (bid >> 6);
    const int h = bh % Hh, b = bh / Hh;

    const size_t rs = 2 * Cdim;  // 1536
    const ushort* qbase = qk + (size_t)b * Nseq * rs + h * Dd;
    const ushort* kbase = qbase + Cdim;
    // vt is [768][16384]: row = h*64+d, col = b*1024 + n
    const ushort* vbase = vt + (size_t)(h * Dd) * LDV + (size_t)b * Nseq;

    // Q fragments in registers (pre-scaled by SCALE*log2e at gemm1).
    // B-op for S^T: lane holds Q[q=l32][d=kc*16+hi*8+j]
    short8 aq[4];
    {
        int q = qt * 128 + w * 32 + l32;
#pragma unroll
        for (int kc = 0; kc < 4; ++kc)
            aq[kc] = *(const short8*)&qbase[(size_t)q * rs + kc * 16 + hi * 8];
    }

    auto stage = [&](int kt64, int buf) {
#pragma unroll
        for (int i = 0; i < 2; ++i) {
            int r0 = (w * 2 + i) * 8;
            int row = r0 + srow;
            int cs = (schunk ^ (row & 7)) * 8;
            gld16(&Ks[buf][r0 * 64], &kbase[(size_t)(kt64 * 64 + row) * rs + cs]);
            gld16(&Vts[buf][r0 * 64], &vbase[(size_t)row * LDV + kt64 * 64 + cs]);
        }
    };

    floatx16 o[2];
    o[0] = (floatx16)0.0f;
    o[1] = (floatx16)0.0f;
    float lsum = 0.f;

    stage(0, 0);
    for (int kt = 0; kt < Nseq / 64; ++kt) {
        __syncthreads();  // drains DMA for tile kt; guards buf reuse
        if (kt + 1 < Nseq / 64) stage(kt + 1, (kt + 1) & 1);
        const ushort* Kb = Ks[kt & 1];
        const ushort* Vb = Vts[kt & 1];

        // S^T = K Q^T : st[km] reg r = S^T[key=km*32+(r&3)+8*(r>>2)+4*hi][q=l32]
        floatx16 st[2];
        st[0] = (floatx16)0.0f;
        st[1] = (floatx16)0.0f;
        __builtin_amdgcn_s_setprio(1);
#pragma unroll
        for (int kc = 0; kc < 4; ++kc) {
            const int cs = ((kc * 2 + hi) ^ (l32 & 7)) * 8;
            short8 ak0 = *(const short8*)&Kb[l32 * 64 + cs];
            short8 ak1 = *(const short8*)&Kb[(32 + l32) * 64 + cs];
            st[0] = __builtin_amdgcn_mfma_f32_32x32x16_bf16(ak0, aq[kc], st[0], 0, 0, 0);
            st[1] = __builtin_amdgcn_mfma_f32_32x32x16_bf16(ak1, aq[kc], st[1], 0, 0, 0);
        }
        __builtin_amdgcn_s_setprio(0);

#pragma unroll
        for (int km = 0; km < 2; ++km) {
            // p = 2^s (Q pre-scaled by log2e); all 16 values belong to q=l32.
            // key(p[r]) = km*32 + (r&3) + 8*(r>>2) + 4*hi
            float p[16];
#pragma unroll
            for (int r = 0; r < 16; ++r) p[r] = fexp2(st[km][r]);
            lsum += (((p[0] + p[1]) + (p[2] + p[3])) +
                     ((p[4] + p[5]) + (p[6] + p[7]))) +
                    (((p[8] + p[9]) + (p[10] + p[11])) +
                     ((p[12] + p[13]) + (p[14] + p[15])));
            // pack consecutive-key pairs: c[i] = bf16(p[2i]) | bf16(p[2i+1])<<16
            uint c[8];
#pragma unroll
            for (int i = 0; i < 8; ++i) {
                union { __hip_bfloat162 h2; uint u; } cv;
                cv.h2 = __float22bfloat162_rn(make_float2(p[2 * i], p[2 * i + 1]));
                c[i] = cv.u;
            }
            // half-wave exchange: A-frag word jw holds keys (8hi+2jw, 8hi+2jw+1)
            uint wd[8];
#if __has_builtin(__builtin_amdgcn_permlane32_swap)
            uint2v r02 = __builtin_amdgcn_permlane32_swap(c[0], c[2], false, false);
            uint2v r13 = __builtin_amdgcn_permlane32_swap(c[1], c[3], false, false);
            uint2v r46 = __builtin_amdgcn_permlane32_swap(c[4], c[6], false, false);
            uint2v r57 = __builtin_amdgcn_permlane32_swap(c[5], c[7], false, false);
            wd[0] = r02.x; wd[2] = r02.y;
            wd[1] = r13.x; wd[3] = r13.y;
            wd[4] = r46.x; wd[6] = r46.y;
            wd[5] = r57.x; wd[7] = r57.y;
#else
            uint x0 = __shfl_xor(c[0], 32), x1 = __shfl_xor(c[1], 32);
            uint x2 = __shfl_xor(c[2], 32), x3 = __shfl_xor(c[3], 32);
            uint x4 = __shfl_xor(c[4], 32), x5 = __shfl_xor(c[5], 32);
            uint x6 = __shfl_xor(c[6], 32), x7 = __shfl_xor(c[7], 32);
            wd[0] = hi ? x2 : c[0]; wd[1] = hi ? x3 : c[1];
            wd[2] = hi ? c[2] : x0; wd[3] = hi ? c[3] : x1;
            wd[4] = hi ? x6 : c[4]; wd[5] = hi ? x7 : c[5];
            wd[6] = hi ? c[6] : x4; wd[7] = hi ? c[7] : x5;
#endif
            union { uint u[4]; short8 s; } af0, af1;
            af0.u[0] = wd[0]; af0.u[1] = wd[1]; af0.u[2] = wd[2]; af0.u[3] = wd[3];
            af1.u[0] = wd[4]; af1.u[1] = wd[5]; af1.u[2] = wd[6]; af1.u[3] = wd[7];

            // O[q][d] += P V : B-op = V[key][d=l32+dblk*32] from Vts[d][key]
            __builtin_amdgcn_s_setprio(1);
#pragma unroll
            for (int dblk = 0; dblk < 2; ++dblk) {
                const int row = dblk * 32 + l32;
#pragma unroll
                for (int ks = 0; ks < 2; ++ks) {
                    const int ch = ((km * 4 + ks * 2 + hi) ^ (l32 & 7)) * 8;
                    short8 bv = *(const short8*)&Vb[row * 64 + ch];
                    o[dblk] = __builtin_amdgcn_mfma_f32_32x32x16_bf16(
                        ks ? af1.s : af0.s, bv, o[dblk], 0, 0, 0);
                }
            }
            __builtin_amdgcn_s_setprio(0);
        }
    }

    // full row-sum: partner half-wave holds the other 32 keys per tile
    float lf = lsum + __shfl_xor(lsum, 32);
    float linv = __builtin_amdgcn_rcpf(lf);

    // O C-layout: col = d = l32 (+dblk*32), row = q = (r&3)+8*(r>>2)+4*hi
    const int qg0 = qt * 128 + w * 32;
#pragma unroll
    for (int r = 0; r < 16; ++r) {
        int rowq = (r & 3) + 8 * (r >> 2) + 4 * hi;
        float li = __shfl(linv, rowq);
        int q = qg0 + rowq;
#pragma unroll
        for (int dblk = 0; dblk < 2; ++dblk) {
            int d = dblk * 32 + l32;
            outp[((size_t)(b * Nseq + q)) * Cdim + h * Dd + d] =
                f2bs(o[dblk][r] * li);
        }
    }
}

extern "C" void kernel_launch(void* const* d_in, const int* in_sizes, int n_in,
                              void* d_out, int out_size, void* d_ws, size_t ws_size,
                              hipStream_t stream) {
    const float* x      = (const float*)d_in[0];
    const float* qkv_w  = (const float*)d_in[1];
    const float* qkv_b  = (const float*)d_in[2];
    const float* proj_w = (const float*)d_in[3];
    const float* proj_b = (const float*)d_in[4];
    float* out = (float*)d_out;

    const int M = Bsz * Nseq;  // 16384
    ushort* xb    = (ushort*)d_ws;                        // [16384x768]
    ushort* qk    = xb + (size_t)M * Cdim;                // [16384x1536]
    ushort* vtbuf = qk + (size_t)M * 2 * Cdim;            // [768][16384]
    ushort* wqkvb = vtbuf + (size_t)Cdim * M;             // [2304x768]
    ushort* wprjb = wqkvb + (size_t)3 * Cdim * Cdim;      // [768x768]
    ushort* attnout = xb;  // xb dead after VT-gemm

    // 0) fp32 -> bf16 pack
    pack_bf16<<<14592, 256, 0, stream>>>(x, qkv_w, proj_w, xb, wqkvb, wprjb);
    // 1a) QK GEMM: X @ Wqk^T -> qk [16384x1536]; Q cols pre-scaled by QSC
    gemm_nt_mfma<ushort><<<dim3(12, 128), 256, 0, stream>>>(
        xb, wqkvb, qkv_b, qk, 2 * Cdim, M, 2 * Cdim, Cdim, 0, Cdim, QSC, 1);
    // 1b) VT GEMM: Wv @ X^T -> vt [768][16384], bias per row; swz=0 (natural
    //     bid mod 8 alignment already groups a B-panel's readers per XCD)
    gemm_nt_mfma<ushort><<<dim3(128, 6), 256, 0, stream>>>(
        wqkvb + (size_t)2 * Cdim * Cdim, xb, qkv_b + 2 * Cdim, vtbuf,
        M, Cdim, M, Cdim, 1, 0, 1.0f, 0);
    // 2) attention
    attn_mfma<<<Bsz * Hh * (Nseq / 128), 256, 0, stream>>>(qk, vtbuf, attnout);
    // 3) projection -> fp32 out
    gemm_nt_mfma<float><<<dim3(6, 128), 256, 0, stream>>>(
        attnout, wprjb, proj_b, out, Cdim, M, Cdim, Cdim, 0, 0, 1.0f, 1);
}

// Round 9
// 293.204 us; speedup vs baseline: 1.1181x; 1.0221x over previous
//
#include <hip/hip_runtime.h>
#include <hip/hip_bf16.h>

// ViT attention, MFMA bf16 pipeline. B=16, N=1024, C=768, H=12, D=64.
// Round 14: attn -> 512-thread blocks, TWO q-tiles (256 q) per block sharing
// the same staged K/V tiles. Per-wave inner loop bit-identical to round-8's
// verified version; 8 waves/block -> 4 blocks/CU = 32 waves/CU (100% occ cap,
// was 12 waves), and K/V DMA per unit compute halves. Gemm side byte-identical
// to round-8 (clean attribution).
// attn: S^T = K*Q^T in 32x32 MFMA, in-register softmax (raw v_exp_f32,
// cvt_pk, permlane32_swap), setprio on MFMA clusters, dbuf K/V staging.
// gemm: round-4 BK=64/2-barrier loop + XCD swizzle on QK/proj (swz=1),
// VT natural alignment (swz=0).
// MFMA 32x32x16 bf16 layouts (m74/m101):
//   A-op: lane holds A[m=lane&31][k=8*(lane>>5)+j]
//   B-op: lane holds B[k=8*(lane>>5)+j][n=lane&31]
//   C/D : reg r = D[row=(r&3)+8*(r>>2)+4*(lane>>5)][col=lane&31]
// MFMA 16x16x32 bf16 layouts (m89/m91):
//   A/B-op: lane(quad,l16) holds [m=l16][k=quad*8+j]
//   C/D   : reg r = D[row=quad*4+r][col=l16]

typedef __attribute__((ext_vector_type(8))) short short8;
typedef __attribute__((ext_vector_type(4))) float floatx4;
typedef __attribute__((ext_vector_type(16))) float floatx16;
typedef __attribute__((ext_vector_type(2))) unsigned int uint2v;

constexpr int Bsz = 16, Nseq = 1024, Cdim = 768, Hh = 12, Dd = 64;
constexpr float QSC = 0.1803368801f;       // 64^-0.5 * log2(e), folded into Q
constexpr int LDV = Bsz * Nseq;            // 16384, vt leading dim

__device__ __forceinline__ ushort f2bs(float f) {
    union { __hip_bfloat16 h; ushort u; } cv;
    cv.h = __float2bfloat16(f);
    return cv.u;
}
__device__ __forceinline__ void stF(float* p, float v) { *p = v; }
__device__ __forceinline__ void stF(ushort* p, float v) { *p = f2bs(v); }

__device__ __forceinline__ float fexp2(float x) {
#if __has_builtin(__builtin_amdgcn_exp2f)
    return __builtin_amdgcn_exp2f(x);   // raw v_exp_f32; inputs |x|<~40, safe
#else
    return exp2f(x);
#endif
}

// async 16B/lane global->LDS DMA. lds must be wave-uniform; HW adds lane*16.
__device__ __forceinline__ void gld16(void* lds, const void* g) {
    __builtin_amdgcn_global_load_lds(
        (const __attribute__((address_space(1))) unsigned int*)g,
        (__attribute__((address_space(3))) unsigned int*)lds, 16, 0, 0);
}

// fp32 -> bf16 pack: x | qkv_w | proj_w
__global__ __launch_bounds__(256) void pack_bf16(
        const float* __restrict__ x, const float* __restrict__ w1,
        const float* __restrict__ w2, ushort* __restrict__ xb,
        ushort* __restrict__ w1b, ushort* __restrict__ w2b) {
    const size_t n0 = (size_t)Bsz * Nseq * Cdim;   // 12,582,912
    const size_t n1 = (size_t)3 * Cdim * Cdim;     //  1,769,472
    size_t i = ((size_t)blockIdx.x * 256 + threadIdx.x) * 4;
    const float* src;
    ushort* dst;
    if (i < n0) { src = x; dst = xb; }
    else if (i < n0 + n1) { i -= n0; src = w1; dst = w1b; }
    else { i -= n0 + n1; src = w2; dst = w2b; }
    float4 v = *(const float4*)&src[i];
    *(ushort4*)&dst[i] = make_ushort4(f2bs(v.x), f2bs(v.y), f2bs(v.z), f2bs(v.w));
}

// C = A[M,K] @ Bw[N,K]^T + bias. 128x128 tile, BK=64, 256 thr, 4 waves.
// bias_row ? bias[row] : bias[col]. Cols < qsplit scaled by qscale.
// swz: XCD-chunked block remap (use when consecutive blocks share A-panel).
template <typename TO>
__global__ __launch_bounds__(256) void gemm_nt_mfma(
        const ushort* __restrict__ A, const ushort* __restrict__ Bw,
        const float* __restrict__ bias, TO* __restrict__ C0,
        int ld0, int M, int N, int K, int bias_row, int qsplit, float qscale,
        int swz) {
    __shared__ ushort As[128 * 64];   // [row][k] unpadded, XOR-8 swizzled
    __shared__ ushort Bs[128 * 64];
    const int t = threadIdx.x;
    const int lane = t & 63;
    const int w = t >> 6;
    const int quad = lane >> 4;
    const int l16 = lane & 15;

    int bidl = blockIdx.y * gridDim.x + blockIdx.x;
    if (swz) {
        const int nwg = gridDim.x * gridDim.y;   // multiple of 8 for our grids
        const int cpx = nwg >> 3;
        bidl = (bidl & 7) * cpx + (bidl >> 3);   // bijective: nwg % 8 == 0
    }
    const int m0 = (bidl / gridDim.x) * 128;
    const int n0 = (bidl % gridDim.x) * 128;

    const int mw = (w >> 1) * 64;
    const int nw = (w & 1) * 64;
    const int srow = lane >> 3;
    const int schunk = lane & 7;

    floatx4 acc[4][4];
#pragma unroll
    for (int i = 0; i < 4; ++i)
#pragma unroll
        for (int j = 0; j < 4; ++j) acc[i][j] = (floatx4)0.0f;

    for (int k0 = 0; k0 < K; k0 += 64) {
        __syncthreads();
#pragma unroll
        for (int i = 0; i < 4; ++i) {
            int r0 = (w * 4 + i) * 8;
            int row = r0 + srow;
            int cs = (schunk ^ (row & 7)) * 8;
            gld16(&As[r0 * 64], &A[(size_t)(m0 + row) * K + k0 + cs]);
            gld16(&Bs[r0 * 64], &Bw[(size_t)(n0 + row) * K + k0 + cs]);
        }
        __syncthreads();

#pragma unroll
        for (int kk = 0; kk < 2; ++kk) {
            const int pc = ((kk * 4 + quad) ^ (l16 & 7)) * 8;
            short8 af[4], bfr[4];
#pragma unroll
            for (int i = 0; i < 4; ++i)
                af[i] = *(const short8*)&As[(mw + i * 16 + l16) * 64 + pc];
#pragma unroll
            for (int j = 0; j < 4; ++j)
                bfr[j] = *(const short8*)&Bs[(nw + j * 16 + l16) * 64 + pc];
#pragma unroll
            for (int i = 0; i < 4; ++i)
#pragma unroll
                for (int j = 0; j < 4; ++j)
                    acc[i][j] = __builtin_amdgcn_mfma_f32_16x16x32_bf16(
                        af[i], bfr[j], acc[i][j], 0, 0, 0);
        }
    }

    if (bias_row) {
        float brv[4][4];
#pragma unroll
        for (int i = 0; i < 4; ++i)
#pragma unroll
            for (int r = 0; r < 4; ++r)
                brv[i][r] = bias[m0 + mw + i * 16 + quad * 4 + r];
#pragma unroll
        for (int j = 0; j < 4; ++j) {
            int col = n0 + nw + j * 16 + l16;
#pragma unroll
            for (int i = 0; i < 4; ++i)
#pragma unroll
                for (int r = 0; r < 4; ++r) {
                    int row = m0 + mw + i * 16 + quad * 4 + r;
                    stF(&C0[(size_t)row * ld0 + col], acc[i][j][r] + brv[i][r]);
                }
        }
    } else {
#pragma unroll
        for (int j = 0; j < 4; ++j) {
            int col = n0 + nw + j * 16 + l16;
            float bc = bias[col];
            float sc = (col < qsplit) ? qscale : 1.0f;
#pragma unroll
            for (int i = 0; i < 4; ++i)
#pragma unroll
                for (int r = 0; r < 4; ++r) {
                    int row = m0 + mw + i * 16 + quad * 4 + r;
                    stF(&C0[(size_t)row * ld0 + col], (acc[i][j][r] + bc) * sc);
                }
        }
    }
}

// Flash attention, no-max softmax, S^T formulation, 32x32x16 MFMA,
// in-register P (permlane32_swap half-exchange), no P LDS.
// Block = (b,h, 256-q slab): 8 waves, 512 thr; wave w owns q rows w*32..+31.
// KV tiles of 64 shared by all 8 waves, double-buffered staging.
__global__ __launch_bounds__(512, 4) void attn_mfma(
        const ushort* __restrict__ qk, const ushort* __restrict__ vt,
        ushort* __restrict__ outp) {
    __shared__ ushort Ks[2][64 * 64];   // [key][d], XOR-8 swizzled
    __shared__ ushort Vts[2][64 * 64];  // [d][key], XOR-8 swizzled

    const int t = threadIdx.x;
    const int lane = t & 63;
    const int w = t >> 6;               // 0..7
    const int l32 = lane & 31;
    const int hi = lane >> 5;
    const int srow = lane >> 3;
    const int schunk = lane & 7;

    // XCD pairing: bid and bid+8 share one (b,h) -> same XCD under mod-8
    // round-robin dispatch; 4 q-slabs of one bh land consecutively there.
    const int bid = blockIdx.x;          // 768 blocks = 192 bh x 4 slabs
    const int qt = (bid >> 3) & 3;       // q-slab 0..3 (256 q each)
    const int bh = (bid & 7) + 8 * (bid >> 5);
    const int h = bh % Hh, b = bh / Hh;

    const size_t rs = 2 * Cdim;  // 1536
    const ushort* qbase = qk + (size_t)b * Nseq * rs + h * Dd;
    const ushort* kbase = qbase + Cdim;
    // vt is [768][16384]: row = h*64+d, col = b*1024 + n
    const ushort* vbase = vt + (size_t)(h * Dd) * LDV + (size_t)b * Nseq;

    // Q fragments in registers (pre-scaled by SCALE*log2e at gemm1).
    // B-op for S^T: lane holds Q[q=l32][d=kc*16+hi*8+j]
    short8 aq[4];
    {
        int q = qt * 256 + w * 32 + l32;
#pragma unroll
        for (int kc = 0; kc < 4; ++kc)
            aq[kc] = *(const short8*)&qbase[(size_t)q * rs + kc * 16 + hi * 8];
    }

    // 8 waves stage 64 rows: wave w covers rows w*8 .. w*8+7
    auto stage = [&](int kt64, int buf) {
        int r0 = w * 8;
        int row = r0 + srow;
        int cs = (schunk ^ (row & 7)) * 8;
        gld16(&Ks[buf][r0 * 64], &kbase[(size_t)(kt64 * 64 + row) * rs + cs]);
        gld16(&Vts[buf][r0 * 64], &vbase[(size_t)row * LDV + kt64 * 64 + cs]);
    };

    floatx16 o[2];
    o[0] = (floatx16)0.0f;
    o[1] = (floatx16)0.0f;
    float lsum = 0.f;

    stage(0, 0);
    for (int kt = 0; kt < Nseq / 64; ++kt) {
        __syncthreads();  // drains DMA for tile kt; guards buf reuse
        if (kt + 1 < Nseq / 64) stage(kt + 1, (kt + 1) & 1);
        const ushort* Kb = Ks[kt & 1];
        const ushort* Vb = Vts[kt & 1];

        // S^T = K Q^T : st[km] reg r = S^T[key=km*32+(r&3)+8*(r>>2)+4*hi][q=l32]
        floatx16 st[2];
        st[0] = (floatx16)0.0f;
        st[1] = (floatx16)0.0f;
        __builtin_amdgcn_s_setprio(1);
#pragma unroll
        for (int kc = 0; kc < 4; ++kc) {
            const int cs = ((kc * 2 + hi) ^ (l32 & 7)) * 8;
            short8 ak0 = *(const short8*)&Kb[l32 * 64 + cs];
            short8 ak1 = *(const short8*)&Kb[(32 + l32) * 64 + cs];
            st[0] = __builtin_amdgcn_mfma_f32_32x32x16_bf16(ak0, aq[kc], st[0], 0, 0, 0);
            st[1] = __builtin_amdgcn_mfma_f32_32x32x16_bf16(ak1, aq[kc], st[1], 0, 0, 0);
        }
        __builtin_amdgcn_s_setprio(0);

#pragma unroll
        for (int km = 0; km < 2; ++km) {
            // p = 2^s (Q pre-scaled by log2e); all 16 values belong to q=l32.
            // key(p[r]) = km*32 + (r&3) + 8*(r>>2) + 4*hi
            float p[16];
#pragma unroll
            for (int r = 0; r < 16; ++r) p[r] = fexp2(st[km][r]);
            lsum += (((p[0] + p[1]) + (p[2] + p[3])) +
                     ((p[4] + p[5]) + (p[6] + p[7]))) +
                    (((p[8] + p[9]) + (p[10] + p[11])) +
                     ((p[12] + p[13]) + (p[14] + p[15])));
            // pack consecutive-key pairs: c[i] = bf16(p[2i]) | bf16(p[2i+1])<<16
            uint c[8];
#pragma unroll
            for (int i = 0; i < 8; ++i) {
                union { __hip_bfloat162 h2; uint u; } cv;
                cv.h2 = __float22bfloat162_rn(make_float2(p[2 * i], p[2 * i + 1]));
                c[i] = cv.u;
            }
            // half-wave exchange: A-frag word jw holds keys (8hi+2jw, 8hi+2jw+1)
            uint wd[8];
#if __has_builtin(__builtin_amdgcn_permlane32_swap)
            uint2v r02 = __builtin_amdgcn_permlane32_swap(c[0], c[2], false, false);
            uint2v r13 = __builtin_amdgcn_permlane32_swap(c[1], c[3], false, false);
            uint2v r46 = __builtin_amdgcn_permlane32_swap(c[4], c[6], false, false);
            uint2v r57 = __builtin_amdgcn_permlane32_swap(c[5], c[7], false, false);
            wd[0] = r02.x; wd[2] = r02.y;
            wd[1] = r13.x; wd[3] = r13.y;
            wd[4] = r46.x; wd[6] = r46.y;
            wd[5] = r57.x; wd[7] = r57.y;
#else
            uint x0 = __shfl_xor(c[0], 32), x1 = __shfl_xor(c[1], 32);
            uint x2 = __shfl_xor(c[2], 32), x3 = __shfl_xor(c[3], 32);
            uint x4 = __shfl_xor(c[4], 32), x5 = __shfl_xor(c[5], 32);
            uint x6 = __shfl_xor(c[6], 32), x7 = __shfl_xor(c[7], 32);
            wd[0] = hi ? x2 : c[0]; wd[1] = hi ? x3 : c[1];
            wd[2] = hi ? c[2] : x0; wd[3] = hi ? c[3] : x1;
            wd[4] = hi ? x6 : c[4]; wd[5] = hi ? x7 : c[5];
            wd[6] = hi ? c[6] : x4; wd[7] = hi ? c[7] : x5;
#endif
            union { uint u[4]; short8 s; } af0, af1;
            af0.u[0] = wd[0]; af0.u[1] = wd[1]; af0.u[2] = wd[2]; af0.u[3] = wd[3];
            af1.u[0] = wd[4]; af1.u[1] = wd[5]; af1.u[2] = wd[6]; af1.u[3] = wd[7];

            // O[q][d] += P V : B-op = V[key][d=l32+dblk*32] from Vts[d][key]
            __builtin_amdgcn_s_setprio(1);
#pragma unroll
            for (int dblk = 0; dblk < 2; ++dblk) {
                const int row = dblk * 32 + l32;
#pragma unroll
                for (int ks = 0; ks < 2; ++ks) {
                    const int ch = ((km * 4 + ks * 2 + hi) ^ (l32 & 7)) * 8;
                    short8 bv = *(const short8*)&Vb[row * 64 + ch];
                    o[dblk] = __builtin_amdgcn_mfma_f32_32x32x16_bf16(
                        ks ? af1.s : af0.s, bv, o[dblk], 0, 0, 0);
                }
            }
            __builtin_amdgcn_s_setprio(0);
        }
    }

    // full row-sum: partner half-wave holds the other 32 keys per tile
    float lf = lsum + __shfl_xor(lsum, 32);
    float linv = __builtin_amdgcn_rcpf(lf);

    // O C-layout: col = d = l32 (+dblk*32), row = q = (r&3)+8*(r>>2)+4*hi
    const int qg0 = qt * 256 + w * 32;
#pragma unroll
    for (int r = 0; r < 16; ++r) {
        int rowq = (r & 3) + 8 * (r >> 2) + 4 * hi;
        float li = __shfl(linv, rowq);
        int q = qg0 + rowq;
#pragma unroll
        for (int dblk = 0; dblk < 2; ++dblk) {
            int d = dblk * 32 + l32;
            outp[((size_t)(b * Nseq + q)) * Cdim + h * Dd + d] =
                f2bs(o[dblk][r] * li);
        }
    }
}

extern "C" void kernel_launch(void* const* d_in, const int* in_sizes, int n_in,
                              void* d_out, int out_size, void* d_ws, size_t ws_size,
                              hipStream_t stream) {
    const float* x      = (const float*)d_in[0];
    const float* qkv_w  = (const float*)d_in[1];
    const float* qkv_b  = (const float*)d_in[2];
    const float* proj_w = (const float*)d_in[3];
    const float* proj_b = (const float*)d_in[4];
    float* out = (float*)d_out;

    const int M = Bsz * Nseq;  // 16384
    ushort* xb    = (ushort*)d_ws;                        // [16384x768]
    ushort* qk    = xb + (size_t)M * Cdim;                // [16384x1536]
    ushort* vtbuf = qk + (size_t)M * 2 * Cdim;            // [768][16384]
    ushort* wqkvb = vtbuf + (size_t)Cdim * M;             // [2304x768]
    ushort* wprjb = wqkvb + (size_t)3 * Cdim * Cdim;      // [768x768]
    ushort* attnout = xb;  // xb dead after VT-gemm

    // 0) fp32 -> bf16 pack
    pack_bf16<<<14592, 256, 0, stream>>>(x, qkv_w, proj_w, xb, wqkvb, wprjb);
    // 1a) QK GEMM: X @ Wqk^T -> qk [16384x1536]; Q cols pre-scaled by QSC
    gemm_nt_mfma<ushort><<<dim3(12, 128), 256, 0, stream>>>(
        xb, wqkvb, qkv_b, qk, 2 * Cdim, M, 2 * Cdim, Cdim, 0, Cdim, QSC, 1);
    // 1b) VT GEMM: Wv @ X^T -> vt [768][16384], bias per row; swz=0 (natural
    //     bid mod 8 alignment already groups a B-panel's readers per XCD)
    gemm_nt_mfma<ushort><<<dim3(128, 6), 256, 0, stream>>>(
        wqkvb + (size_t)2 * Cdim * Cdim, xb, qkv_b + 2 * Cdim, vtbuf,
        M, Cdim, M, Cdim, 1, 0, 1.0f, 0);
    // 2) attention: 768 blocks x 512 threads (2 q-tiles per block)
    attn_mfma<<<Bsz * Hh * (Nseq / 256), 512, 0, stream>>>(qk, vtbuf, attnout);
    // 3) projection -> fp32 out
    gemm_nt_mfma<float><<<dim3(6, 128), 256, 0, stream>>>(
        attnout, wprjb, proj_b, out, Cdim, M, Cdim, Cdim, 0, 0, 1.0f, 1);
}

// Round 10
// 292.068 us; speedup vs baseline: 1.1224x; 1.0039x over previous
//
#include <hip/hip_runtime.h>
#include <hip/hip_bf16.h>

// ViT attention, MFMA bf16 pipeline. B=16, N=1024, C=768, H=12, D=64.
// Round 15: attn critical-path shortening (K-row permutation).
//  - K rows staged into LDS permuted by pi32(l) = 16*b3 + 8*b2 + 4*b4 + (l&3)
//    (bit-rotation, bijective per 32-block). Effect: the 32x32 S^T C-rows a
//    lane owns ARE the keys its PV A-fragment needs -> A-frags assemble
//    lane-locally from cvt_pk pairs; the 8 permlane32_swap/tile cross-half
//    exchanges are DELETED. V stays natural order (A-frag keys now natural).
//    gld16's global addr is per-lane, so the permutation is free at staging.
//  - lsum adds moved AFTER PV MFMA issue (VALU overlaps MFMA pipe).
//  - everything else byte-identical to round-14 (total 293.2 best).
// attn: S^T = K*Q^T in 32x32 MFMA, in-register softmax (raw v_exp_f32,
// cvt_pk), setprio on MFMA clusters, dbuf K/V staging, 512-thr 2-qtile blocks.
// gemm: round-4 BK=64/2-barrier loop + XCD swizzle on QK/proj, VT swz=0.
// MFMA 32x32x16 bf16 layouts (m74/m101):
//   A-op: lane holds A[m=lane&31][k=8*(lane>>5)+j]
//   B-op: lane holds B[k=8*(lane>>5)+j][n=lane&31]
//   C/D : reg r = D[row=(r&3)+8*(r>>2)+4*(lane>>5)][col=lane&31]
// With K-permute, lane's p[r] (km-block) = actual keys:
//   r=0..3 -> 8hi+r | r=4..7 -> 16+8hi+(r-4) | r=8..11 -> 8hi+4+(r-8)
//   | r=12..15 -> 16+8hi+4+(r-12)
// MFMA 16x16x32 bf16 layouts (m89/m91):
//   A/B-op: lane(quad,l16) holds [m=l16][k=quad*8+j]
//   C/D   : reg r = D[row=quad*4+r][col=l16]

typedef __attribute__((ext_vector_type(8))) short short8;
typedef __attribute__((ext_vector_type(4))) float floatx4;
typedef __attribute__((ext_vector_type(16))) float floatx16;

constexpr int Bsz = 16, Nseq = 1024, Cdim = 768, Hh = 12, Dd = 64;
constexpr float QSC = 0.1803368801f;       // 64^-0.5 * log2(e), folded into Q
constexpr int LDV = Bsz * Nseq;            // 16384, vt leading dim

__device__ __forceinline__ ushort f2bs(float f) {
    union { __hip_bfloat16 h; ushort u; } cv;
    cv.h = __float2bfloat16(f);
    return cv.u;
}
__device__ __forceinline__ void stF(float* p, float v) { *p = v; }
__device__ __forceinline__ void stF(ushort* p, float v) { *p = f2bs(v); }

__device__ __forceinline__ float fexp2(float x) {
#if __has_builtin(__builtin_amdgcn_exp2f)
    return __builtin_amdgcn_exp2f(x);   // raw v_exp_f32; inputs |x|<~40, safe
#else
    return exp2f(x);
#endif
}

__device__ __forceinline__ uint pk2(float a, float b) {
    union { __hip_bfloat162 h2; uint u; } cv;
    cv.h2 = __float22bfloat162_rn(make_float2(a, b));
    return cv.u;
}

// async 16B/lane global->LDS DMA. lds must be wave-uniform; HW adds lane*16.
__device__ __forceinline__ void gld16(void* lds, const void* g) {
    __builtin_amdgcn_global_load_lds(
        (const __attribute__((address_space(1))) unsigned int*)g,
        (__attribute__((address_space(3))) unsigned int*)lds, 16, 0, 0);
}

// fp32 -> bf16 pack: x | qkv_w | proj_w
__global__ __launch_bounds__(256) void pack_bf16(
        const float* __restrict__ x, const float* __restrict__ w1,
        const float* __restrict__ w2, ushort* __restrict__ xb,
        ushort* __restrict__ w1b, ushort* __restrict__ w2b) {
    const size_t n0 = (size_t)Bsz * Nseq * Cdim;   // 12,582,912
    const size_t n1 = (size_t)3 * Cdim * Cdim;     //  1,769,472
    size_t i = ((size_t)blockIdx.x * 256 + threadIdx.x) * 4;
    const float* src;
    ushort* dst;
    if (i < n0) { src = x; dst = xb; }
    else if (i < n0 + n1) { i -= n0; src = w1; dst = w1b; }
    else { i -= n0 + n1; src = w2; dst = w2b; }
    float4 v = *(const float4*)&src[i];
    *(ushort4*)&dst[i] = make_ushort4(f2bs(v.x), f2bs(v.y), f2bs(v.z), f2bs(v.w));
}

// C = A[M,K] @ Bw[N,K]^T + bias. 128x128 tile, BK=64, 256 thr, 4 waves.
// bias_row ? bias[row] : bias[col]. Cols < qsplit scaled by qscale.
// swz: XCD-chunked block remap (use when consecutive blocks share A-panel).
template <typename TO>
__global__ __launch_bounds__(256) void gemm_nt_mfma(
        const ushort* __restrict__ A, const ushort* __restrict__ Bw,
        const float* __restrict__ bias, TO* __restrict__ C0,
        int ld0, int M, int N, int K, int bias_row, int qsplit, float qscale,
        int swz) {
    __shared__ ushort As[128 * 64];   // [row][k] unpadded, XOR-8 swizzled
    __shared__ ushort Bs[128 * 64];
    const int t = threadIdx.x;
    const int lane = t & 63;
    const int w = t >> 6;
    const int quad = lane >> 4;
    const int l16 = lane & 15;

    int bidl = blockIdx.y * gridDim.x + blockIdx.x;
    if (swz) {
        const int nwg = gridDim.x * gridDim.y;   // multiple of 8 for our grids
        const int cpx = nwg >> 3;
        bidl = (bidl & 7) * cpx + (bidl >> 3);   // bijective: nwg % 8 == 0
    }
    const int m0 = (bidl / gridDim.x) * 128;
    const int n0 = (bidl % gridDim.x) * 128;

    const int mw = (w >> 1) * 64;
    const int nw = (w & 1) * 64;
    const int srow = lane >> 3;
    const int schunk = lane & 7;

    floatx4 acc[4][4];
#pragma unroll
    for (int i = 0; i < 4; ++i)
#pragma unroll
        for (int j = 0; j < 4; ++j) acc[i][j] = (floatx4)0.0f;

    for (int k0 = 0; k0 < K; k0 += 64) {
        __syncthreads();
#pragma unroll
        for (int i = 0; i < 4; ++i) {
            int r0 = (w * 4 + i) * 8;
            int row = r0 + srow;
            int cs = (schunk ^ (row & 7)) * 8;
            gld16(&As[r0 * 64], &A[(size_t)(m0 + row) * K + k0 + cs]);
            gld16(&Bs[r0 * 64], &Bw[(size_t)(n0 + row) * K + k0 + cs]);
        }
        __syncthreads();

#pragma unroll
        for (int kk = 0; kk < 2; ++kk) {
            const int pc = ((kk * 4 + quad) ^ (l16 & 7)) * 8;
            short8 af[4], bfr[4];
#pragma unroll
            for (int i = 0; i < 4; ++i)
                af[i] = *(const short8*)&As[(mw + i * 16 + l16) * 64 + pc];
#pragma unroll
            for (int j = 0; j < 4; ++j)
                bfr[j] = *(const short8*)&Bs[(nw + j * 16 + l16) * 64 + pc];
#pragma unroll
            for (int i = 0; i < 4; ++i)
#pragma unroll
                for (int j = 0; j < 4; ++j)
                    acc[i][j] = __builtin_amdgcn_mfma_f32_16x16x32_bf16(
                        af[i], bfr[j], acc[i][j], 0, 0, 0);
        }
    }

    if (bias_row) {
        float brv[4][4];
#pragma unroll
        for (int i = 0; i < 4; ++i)
#pragma unroll
            for (int r = 0; r < 4; ++r)
                brv[i][r] = bias[m0 + mw + i * 16 + quad * 4 + r];
#pragma unroll
        for (int j = 0; j < 4; ++j) {
            int col = n0 + nw + j * 16 + l16;
#pragma unroll
            for (int i = 0; i < 4; ++i)
#pragma unroll
                for (int r = 0; r < 4; ++r) {
                    int row = m0 + mw + i * 16 + quad * 4 + r;
                    stF(&C0[(size_t)row * ld0 + col], acc[i][j][r] + brv[i][r]);
                }
        }
    } else {
#pragma unroll
        for (int j = 0; j < 4; ++j) {
            int col = n0 + nw + j * 16 + l16;
            float bc = bias[col];
            float sc = (col < qsplit) ? qscale : 1.0f;
#pragma unroll
            for (int i = 0; i < 4; ++i)
#pragma unroll
                for (int r = 0; r < 4; ++r) {
                    int row = m0 + mw + i * 16 + quad * 4 + r;
                    stF(&C0[(size_t)row * ld0 + col], (acc[i][j][r] + bc) * sc);
                }
        }
    }
}

// Flash attention, no-max softmax, S^T formulation, 32x32x16 MFMA,
// in-register P (K-permuted staging -> lane-local A-frags), no P LDS.
// Block = (b,h, 256-q slab): 8 waves, 512 thr; wave w owns q rows w*32..+31.
// KV tiles of 64 shared by all 8 waves, double-buffered staging.
__global__ __launch_bounds__(512, 4) void attn_mfma(
        const ushort* __restrict__ qk, const ushort* __restrict__ vt,
        ushort* __restrict__ outp) {
    __shared__ ushort Ks[2][64 * 64];   // [key(permuted)][d], XOR-8 swizzled
    __shared__ ushort Vts[2][64 * 64];  // [d][key(natural)], XOR-8 swizzled

    const int t = threadIdx.x;
    const int lane = t & 63;
    const int w = t >> 6;               // 0..7
    const int l32 = lane & 31;
    const int hi = lane >> 5;
    const int srow = lane >> 3;
    const int schunk = lane & 7;

    // XCD pairing: bid and bid+8 share one (b,h) -> same XCD under mod-8
    // round-robin dispatch; 4 q-slabs of one bh land consecutively there.
    const int bid = blockIdx.x;          // 768 blocks = 192 bh x 4 slabs
    const int qt = (bid >> 3) & 3;       // q-slab 0..3 (256 q each)
    const int bh = (bid & 7) + 8 * (bid >> 5);
    const int h = bh % Hh, b = bh / Hh;

    const size_t rs = 2 * Cdim;  // 1536
    const ushort* qbase = qk + (size_t)b * Nseq * rs + h * Dd;
    const ushort* kbase = qbase + Cdim;
    // vt is [768][16384]: row = h*64+d, col = b*1024 + n
    const ushort* vbase = vt + (size_t)(h * Dd) * LDV + (size_t)b * Nseq;

    // Q fragments in registers (pre-scaled by SCALE*log2e at gemm1).
    // B-op for S^T: lane holds Q[q=l32][d=kc*16+hi*8+j]
    short8 aq[4];
    {
        int q = qt * 256 + w * 32 + l32;
#pragma unroll
        for (int kc = 0; kc < 4; ++kc)
            aq[kc] = *(const short8*)&qbase[(size_t)q * rs + kc * 16 + hi * 8];
    }

    // 8 waves stage 64 rows: wave w covers LDS rows w*8 .. w*8+7.
    // K global row permuted by pi32 (bit-rotation) so S^T C-rows align with
    // PV A-frag key order; V natural. gld16 global addr is per-lane -> free.
    auto stage = [&](int kt64, int buf) {
        int r0 = w * 8;
        int row = r0 + srow;            // LDS row
        int cs = (schunk ^ (row & 7)) * 8;
        int pr = (row & 32) + ((row >> 3) & 1) * 16 + ((row >> 2) & 1) * 8 +
                 ((row >> 4) & 1) * 4 + (row & 3);   // permuted global key
        gld16(&Ks[buf][r0 * 64], &kbase[(size_t)(kt64 * 64 + pr) * rs + cs]);
        gld16(&Vts[buf][r0 * 64], &vbase[(size_t)row * LDV + kt64 * 64 + cs]);
    };

    floatx16 o[2];
    o[0] = (floatx16)0.0f;
    o[1] = (floatx16)0.0f;
    float lsum = 0.f;

    stage(0, 0);
    for (int kt = 0; kt < Nseq / 64; ++kt) {
        __syncthreads();  // drains DMA for tile kt; guards buf reuse
        if (kt + 1 < Nseq / 64) stage(kt + 1, (kt + 1) & 1);
        const ushort* Kb = Ks[kt & 1];
        const ushort* Vb = Vts[kt & 1];

        // S^T = K Q^T (K rows permuted): lane's 16 C-regs = one q row's P for
        // keys {8hi+0..7}+{16+8hi+0..7} per km-block (see header map).
        floatx16 st[2];
        st[0] = (floatx16)0.0f;
        st[1] = (floatx16)0.0f;
        __builtin_amdgcn_s_setprio(1);
#pragma unroll
        for (int kc = 0; kc < 4; ++kc) {
            const int cs = ((kc * 2 + hi) ^ (l32 & 7)) * 8;
            short8 ak0 = *(const short8*)&Kb[l32 * 64 + cs];
            short8 ak1 = *(const short8*)&Kb[(32 + l32) * 64 + cs];
            st[0] = __builtin_amdgcn_mfma_f32_32x32x16_bf16(ak0, aq[kc], st[0], 0, 0, 0);
            st[1] = __builtin_amdgcn_mfma_f32_32x32x16_bf16(ak1, aq[kc], st[1], 0, 0, 0);
        }
        __builtin_amdgcn_s_setprio(0);

#pragma unroll
        for (int km = 0; km < 2; ++km) {
            // p = 2^s (Q pre-scaled by log2e); all 16 belong to q=l32
            float p[16];
#pragma unroll
            for (int r = 0; r < 16; ++r) p[r] = fexp2(st[km][r]);
            // lane-local A-frags (keys natural order thanks to K-permute):
            // ks=0: keys km*32+8hi+{0..7} = p0..3, p8..11
            // ks=1: keys km*32+16+8hi+{0..7} = p4..7, p12..15
            union { uint u[4]; short8 s; } af0, af1;
            af0.u[0] = pk2(p[0], p[1]);
            af0.u[1] = pk2(p[2], p[3]);
            af0.u[2] = pk2(p[8], p[9]);
            af0.u[3] = pk2(p[10], p[11]);
            af1.u[0] = pk2(p[4], p[5]);
            af1.u[1] = pk2(p[6], p[7]);
            af1.u[2] = pk2(p[12], p[13]);
            af1.u[3] = pk2(p[14], p[15]);

            // O[q][d] += P V : B-op = V[key][d=l32+dblk*32] from Vts[d][key]
            __builtin_amdgcn_s_setprio(1);
#pragma unroll
            for (int dblk = 0; dblk < 2; ++dblk) {
                const int row = dblk * 32 + l32;
#pragma unroll
                for (int ks = 0; ks < 2; ++ks) {
                    const int ch = ((km * 4 + ks * 2 + hi) ^ (l32 & 7)) * 8;
                    short8 bv = *(const short8*)&Vb[row * 64 + ch];
                    o[dblk] = __builtin_amdgcn_mfma_f32_32x32x16_bf16(
                        ks ? af1.s : af0.s, bv, o[dblk], 0, 0, 0);
                }
            }
            __builtin_amdgcn_s_setprio(0);

            // row-sum off the critical path (VALU overlaps MFMA pipe)
            lsum += (((p[0] + p[1]) + (p[2] + p[3])) +
                     ((p[4] + p[5]) + (p[6] + p[7]))) +
                    (((p[8] + p[9]) + (p[10] + p[11])) +
                     ((p[12] + p[13]) + (p[14] + p[15])));
        }
    }

    // full row-sum: partner half-wave holds the other 32 keys per tile
    float lf = lsum + __shfl_xor(lsum, 32);
    float linv = __builtin_amdgcn_rcpf(lf);

    // O C-layout: col = d = l32 (+dblk*32), row = q = (r&3)+8*(r>>2)+4*hi
    const int qg0 = qt * 256 + w * 32;
#pragma unroll
    for (int r = 0; r < 16; ++r) {
        int rowq = (r & 3) + 8 * (r >> 2) + 4 * hi;
        float li = __shfl(linv, rowq);
        int q = qg0 + rowq;
#pragma unroll
        for (int dblk = 0; dblk < 2; ++dblk) {
            int d = dblk * 32 + l32;
            outp[((size_t)(b * Nseq + q)) * Cdim + h * Dd + d] =
                f2bs(o[dblk][r] * li);
        }
    }
}

extern "C" void kernel_launch(void* const* d_in, const int* in_sizes, int n_in,
                              void* d_out, int out_size, void* d_ws, size_t ws_size,
                              hipStream_t stream) {
    const float* x      = (const float*)d_in[0];
    const float* qkv_w  = (const float*)d_in[1];
    const float* qkv_b  = (const float*)d_in[2];
    const float* proj_w = (const float*)d_in[3];
    const float* proj_b = (const float*)d_in[4];
    float* out = (float*)d_out;

    const int M = Bsz * Nseq;  // 16384
    ushort* xb    = (ushort*)d_ws;                        // [16384x768]
    ushort* qk    = xb + (size_t)M * Cdim;                // [16384x1536]
    ushort* vtbuf = qk + (size_t)M * 2 * Cdim;            // [768][16384]
    ushort* wqkvb = vtbuf + (size_t)Cdim * M;             // [2304x768]
    ushort* wprjb = wqkvb + (size_t)3 * Cdim * Cdim;      // [768x768]
    ushort* attnout = xb;  // xb dead after VT-gemm

    // 0) fp32 -> bf16 pack
    pack_bf16<<<14592, 256, 0, stream>>>(x, qkv_w, proj_w, xb, wqkvb, wprjb);
    // 1a) QK GEMM: X @ Wqk^T -> qk [16384x1536]; Q cols pre-scaled by QSC
    gemm_nt_mfma<ushort><<<dim3(12, 128), 256, 0, stream>>>(
        xb, wqkvb, qkv_b, qk, 2 * Cdim, M, 2 * Cdim, Cdim, 0, Cdim, QSC, 1);
    // 1b) VT GEMM: Wv @ X^T -> vt [768][16384], bias per row; swz=0 (natural
    //     bid mod 8 alignment already groups a B-panel's readers per XCD)
    gemm_nt_mfma<ushort><<<dim3(128, 6), 256, 0, stream>>>(
        wqkvb + (size_t)2 * Cdim * Cdim, xb, qkv_b + 2 * Cdim, vtbuf,
        M, Cdim, M, Cdim, 1, 0, 1.0f, 0);
    // 2) attention: 768 blocks x 512 threads (2 q-tiles per block)
    attn_mfma<<<Bsz * Hh * (Nseq / 256), 512, 0, stream>>>(qk, vtbuf, attnout);
    // 3) projection -> fp32 out
    gemm_nt_mfma<float><<<dim3(6, 128), 256, 0, stream>>>(
        attnout, wprjb, proj_b, out, Cdim, M, Cdim, Cdim, 0, 0, 1.0f, 1);
}

// Round 11
// 287.960 us; speedup vs baseline: 1.1384x; 1.0143x over previous
//
#include <hip/hip_runtime.h>
#include <hip/hip_bf16.h>

// ViT attention, MFMA bf16 pipeline. B=16, N=1024, C=768, H=12, D=64.
// Round 16: QK-gemm and VT-gemm MERGED into one 2304-block dispatch.
//  - The two gemms are independent (disjoint outputs, shared read-only
//    inputs). Merging lets VT's 768 blocks backfill QK's dispatch tail
//    (1536 blocks = 1.5 occupancy-waves at 4 blocks/CU -> ~512-block tail
//    ran half-empty) and removes one launch gap. Body factored into a
//    __device__ function, inner loop bit-identical to round-10's verified
//    gemm. QK keeps XCD swizzle in its 1536-prefix; VT natural (1536%8==0
//    preserves its mod-8 B-panel/XCD alignment).
//  - pack / attn / proj byte-identical to round-15 (292.1 us best).
// attn: S^T = K*Q^T in 32x32 MFMA, K-row permuted staging (lane-local PV
// A-frags, no cross-lane exchange), in-register softmax (v_exp_f32, cvt_pk),
// setprio on MFMA clusters, dbuf K/V, 512-thr 2-qtile blocks.
// gemm: BK=64 / 2-barrier loop, gld16 w=16, XOR-8 chunk swizzle.
// MFMA 32x32x16 bf16 layouts (m74/m101):
//   A-op: lane holds A[m=lane&31][k=8*(lane>>5)+j]
//   B-op: lane holds B[k=8*(lane>>5)+j][n=lane&31]
//   C/D : reg r = D[row=(r&3)+8*(r>>2)+4*(lane>>5)][col=lane&31]
// MFMA 16x16x32 bf16 layouts (m89/m91):
//   A/B-op: lane(quad,l16) holds [m=l16][k=quad*8+j]
//   C/D   : reg r = D[row=quad*4+r][col=l16]

typedef __attribute__((ext_vector_type(8))) short short8;
typedef __attribute__((ext_vector_type(4))) float floatx4;
typedef __attribute__((ext_vector_type(16))) float floatx16;

constexpr int Bsz = 16, Nseq = 1024, Cdim = 768, Hh = 12, Dd = 64;
constexpr float QSC = 0.1803368801f;       // 64^-0.5 * log2(e), folded into Q
constexpr int LDV = Bsz * Nseq;            // 16384, vt leading dim

__device__ __forceinline__ ushort f2bs(float f) {
    union { __hip_bfloat16 h; ushort u; } cv;
    cv.h = __float2bfloat16(f);
    return cv.u;
}
__device__ __forceinline__ void stF(float* p, float v) { *p = v; }
__device__ __forceinline__ void stF(ushort* p, float v) { *p = f2bs(v); }

__device__ __forceinline__ float fexp2(float x) {
#if __has_builtin(__builtin_amdgcn_exp2f)
    return __builtin_amdgcn_exp2f(x);   // raw v_exp_f32; inputs |x|<~40, safe
#else
    return exp2f(x);
#endif
}

__device__ __forceinline__ uint pk2(float a, float b) {
    union { __hip_bfloat162 h2; uint u; } cv;
    cv.h2 = __float22bfloat162_rn(make_float2(a, b));
    return cv.u;
}

// async 16B/lane global->LDS DMA. lds must be wave-uniform; HW adds lane*16.
__device__ __forceinline__ void gld16(void* lds, const void* g) {
    __builtin_amdgcn_global_load_lds(
        (const __attribute__((address_space(1))) unsigned int*)g,
        (__attribute__((address_space(3))) unsigned int*)lds, 16, 0, 0);
}

// fp32 -> bf16 pack: x | qkv_w | proj_w
__global__ __launch_bounds__(256) void pack_bf16(
        const float* __restrict__ x, const float* __restrict__ w1,
        const float* __restrict__ w2, ushort* __restrict__ xb,
        ushort* __restrict__ w1b, ushort* __restrict__ w2b) {
    const size_t n0 = (size_t)Bsz * Nseq * Cdim;   // 12,582,912
    const size_t n1 = (size_t)3 * Cdim * Cdim;     //  1,769,472
    size_t i = ((size_t)blockIdx.x * 256 + threadIdx.x) * 4;
    const float* src;
    ushort* dst;
    if (i < n0) { src = x; dst = xb; }
    else if (i < n0 + n1) { i -= n0; src = w1; dst = w1b; }
    else { i -= n0 + n1; src = w2; dst = w2b; }
    float4 v = *(const float4*)&src[i];
    *(ushort4*)&dst[i] = make_ushort4(f2bs(v.x), f2bs(v.y), f2bs(v.z), f2bs(v.w));
}

// Shared GEMM block body: C = A[*,K] @ Bw[*,K]^T + bias on a 128x128 tile at
// (m0,n0) = (bidl/gx, bidl%gx)*128. BK=64, 2-barrier loop, 4 waves.
// bias_row ? bias[row] : bias[col]. Cols < qsplit scaled by qscale.
template <typename TO>
__device__ __forceinline__ void gemm_body(
        ushort* As, ushort* Bs,
        const ushort* __restrict__ A, const ushort* __restrict__ Bw,
        const float* __restrict__ bias, TO* __restrict__ C0,
        int ld0, int gx, int bidl, int K, int bias_row, int qsplit,
        float qscale) {
    const int t = threadIdx.x;
    const int lane = t & 63;
    const int w = t >> 6;
    const int quad = lane >> 4;
    const int l16 = lane & 15;
    const int m0 = (bidl / gx) * 128;
    const int n0 = (bidl % gx) * 128;

    const int mw = (w >> 1) * 64;
    const int nw = (w & 1) * 64;
    const int srow = lane >> 3;
    const int schunk = lane & 7;

    floatx4 acc[4][4];
#pragma unroll
    for (int i = 0; i < 4; ++i)
#pragma unroll
        for (int j = 0; j < 4; ++j) acc[i][j] = (floatx4)0.0f;

    for (int k0 = 0; k0 < K; k0 += 64) {
        __syncthreads();
#pragma unroll
        for (int i = 0; i < 4; ++i) {
            int r0 = (w * 4 + i) * 8;
            int row = r0 + srow;
            int cs = (schunk ^ (row & 7)) * 8;
            gld16(&As[r0 * 64], &A[(size_t)(m0 + row) * K + k0 + cs]);
            gld16(&Bs[r0 * 64], &Bw[(size_t)(n0 + row) * K + k0 + cs]);
        }
        __syncthreads();

#pragma unroll
        for (int kk = 0; kk < 2; ++kk) {
            const int pc = ((kk * 4 + quad) ^ (l16 & 7)) * 8;
            short8 af[4], bfr[4];
#pragma unroll
            for (int i = 0; i < 4; ++i)
                af[i] = *(const short8*)&As[(mw + i * 16 + l16) * 64 + pc];
#pragma unroll
            for (int j = 0; j < 4; ++j)
                bfr[j] = *(const short8*)&Bs[(nw + j * 16 + l16) * 64 + pc];
#pragma unroll
            for (int i = 0; i < 4; ++i)
#pragma unroll
                for (int j = 0; j < 4; ++j)
                    acc[i][j] = __builtin_amdgcn_mfma_f32_16x16x32_bf16(
                        af[i], bfr[j], acc[i][j], 0, 0, 0);
        }
    }

    if (bias_row) {
        float brv[4][4];
#pragma unroll
        for (int i = 0; i < 4; ++i)
#pragma unroll
            for (int r = 0; r < 4; ++r)
                brv[i][r] = bias[m0 + mw + i * 16 + quad * 4 + r];
#pragma unroll
        for (int j = 0; j < 4; ++j) {
            int col = n0 + nw + j * 16 + l16;
#pragma unroll
            for (int i = 0; i < 4; ++i)
#pragma unroll
                for (int r = 0; r < 4; ++r) {
                    int row = m0 + mw + i * 16 + quad * 4 + r;
                    stF(&C0[(size_t)row * ld0 + col], acc[i][j][r] + brv[i][r]);
                }
        }
    } else {
#pragma unroll
        for (int j = 0; j < 4; ++j) {
            int col = n0 + nw + j * 16 + l16;
            float bc = bias[col];
            float sc = (col < qsplit) ? qscale : 1.0f;
#pragma unroll
            for (int i = 0; i < 4; ++i)
#pragma unroll
                for (int r = 0; r < 4; ++r) {
                    int row = m0 + mw + i * 16 + quad * 4 + r;
                    stF(&C0[(size_t)row * ld0 + col], (acc[i][j][r] + bc) * sc);
                }
        }
    }
}

// Fused QK + VT gemms: blocks 0..1535 compute qk (XCD-swizzled), blocks
// 1536..2303 compute vt (natural order; 1536%8==0 keeps mod-8 alignment).
__global__ __launch_bounds__(256) void gemm_qkvt(
        const ushort* __restrict__ xb, const ushort* __restrict__ wqkvb,
        const float* __restrict__ qkv_b, ushort* __restrict__ qk,
        ushort* __restrict__ vt) {
    __shared__ ushort As[128 * 64];
    __shared__ ushort Bs[128 * 64];
    const int bid = blockIdx.x;
    if (bid < 1536) {
        // QK: X[16384x768] @ Wqk[1536x768]^T -> qk, ld 1536, Q cols scaled
        const int bidl = (bid & 7) * 192 + (bid >> 3);   // XCD-chunked, nwg=1536
        gemm_body<ushort>(As, Bs, xb, wqkvb, qkv_b, qk,
                          2 * Cdim, 12, bidl, Cdim, 0, Cdim, QSC);
    } else {
        // VT: Wv[768x768] @ X[16384x768]^T -> vt[768][16384], bias per row
        const int bidl = bid - 1536;                     // gx=128 (n over 16384)
        gemm_body<ushort>(As, Bs, wqkvb + (size_t)2 * Cdim * Cdim, xb,
                          qkv_b + 2 * Cdim, vt, LDV, 128, bidl, Cdim, 1, 0,
                          1.0f);
    }
}

// Standalone gemm (proj): same body, grid-mapped, optional XCD swizzle.
template <typename TO>
__global__ __launch_bounds__(256) void gemm_nt_mfma(
        const ushort* __restrict__ A, const ushort* __restrict__ Bw,
        const float* __restrict__ bias, TO* __restrict__ C0,
        int ld0, int M, int N, int K, int bias_row, int qsplit, float qscale,
        int swz) {
    __shared__ ushort As[128 * 64];
    __shared__ ushort Bs[128 * 64];
    int bidl = blockIdx.y * gridDim.x + blockIdx.x;
    if (swz) {
        const int nwg = gridDim.x * gridDim.y;   // multiple of 8 for our grids
        const int cpx = nwg >> 3;
        bidl = (bidl & 7) * cpx + (bidl >> 3);   // bijective: nwg % 8 == 0
    }
    gemm_body<TO>(As, Bs, A, Bw, bias, C0, ld0, gridDim.x, bidl, K, bias_row,
                  qsplit, qscale);
}

// Flash attention, no-max softmax, S^T formulation, 32x32x16 MFMA,
// in-register P (K-permuted staging -> lane-local A-frags), no P LDS.
// Block = (b,h, 256-q slab): 8 waves, 512 thr; wave w owns q rows w*32..+31.
// KV tiles of 64 shared by all 8 waves, double-buffered staging.
__global__ __launch_bounds__(512, 4) void attn_mfma(
        const ushort* __restrict__ qk, const ushort* __restrict__ vt,
        ushort* __restrict__ outp) {
    __shared__ ushort Ks[2][64 * 64];   // [key(permuted)][d], XOR-8 swizzled
    __shared__ ushort Vts[2][64 * 64];  // [d][key(natural)], XOR-8 swizzled

    const int t = threadIdx.x;
    const int lane = t & 63;
    const int w = t >> 6;               // 0..7
    const int l32 = lane & 31;
    const int hi = lane >> 5;
    const int srow = lane >> 3;
    const int schunk = lane & 7;

    // XCD pairing: bid and bid+8 share one (b,h) -> same XCD under mod-8
    // round-robin dispatch; 4 q-slabs of one bh land consecutively there.
    const int bid = blockIdx.x;          // 768 blocks = 192 bh x 4 slabs
    const int qt = (bid >> 3) & 3;       // q-slab 0..3 (256 q each)
    const int bh = (bid & 7) + 8 * (bid >> 5);
    const int h = bh % Hh, b = bh / Hh;

    const size_t rs = 2 * Cdim;  // 1536
    const ushort* qbase = qk + (size_t)b * Nseq * rs + h * Dd;
    const ushort* kbase = qbase + Cdim;
    // vt is [768][16384]: row = h*64+d, col = b*1024 + n
    const ushort* vbase = vt + (size_t)(h * Dd) * LDV + (size_t)b * Nseq;

    // Q fragments in registers (pre-scaled by SCALE*log2e at gemm1).
    // B-op for S^T: lane holds Q[q=l32][d=kc*16+hi*8+j]
    short8 aq[4];
    {
        int q = qt * 256 + w * 32 + l32;
#pragma unroll
        for (int kc = 0; kc < 4; ++kc)
            aq[kc] = *(const short8*)&qbase[(size_t)q * rs + kc * 16 + hi * 8];
    }

    // 8 waves stage 64 rows: wave w covers LDS rows w*8 .. w*8+7.
    // K global row permuted by pi32 (bit-rotation) so S^T C-rows align with
    // PV A-frag key order; V natural. gld16 global addr is per-lane -> free.
    auto stage = [&](int kt64, int buf) {
        int r0 = w * 8;
        int row = r0 + srow;            // LDS row
        int cs = (schunk ^ (row & 7)) * 8;
        int pr = (row & 32) + ((row >> 3) & 1) * 16 + ((row >> 2) & 1) * 8 +
                 ((row >> 4) & 1) * 4 + (row & 3);   // permuted global key
        gld16(&Ks[buf][r0 * 64], &kbase[(size_t)(kt64 * 64 + pr) * rs + cs]);
        gld16(&Vts[buf][r0 * 64], &vbase[(size_t)row * LDV + kt64 * 64 + cs]);
    };

    floatx16 o[2];
    o[0] = (floatx16)0.0f;
    o[1] = (floatx16)0.0f;
    float lsum = 0.f;

    stage(0, 0);
    for (int kt = 0; kt < Nseq / 64; ++kt) {
        __syncthreads();  // drains DMA for tile kt; guards buf reuse
        if (kt + 1 < Nseq / 64) stage(kt + 1, (kt + 1) & 1);
        const ushort* Kb = Ks[kt & 1];
        const ushort* Vb = Vts[kt & 1];

        // S^T = K Q^T (K rows permuted): lane's 16 C-regs = one q row's P for
        // keys {8hi+0..7}+{16+8hi+0..7} per km-block.
        floatx16 st[2];
        st[0] = (floatx16)0.0f;
        st[1] = (floatx16)0.0f;
        __builtin_amdgcn_s_setprio(1);
#pragma unroll
        for (int kc = 0; kc < 4; ++kc) {
            const int cs = ((kc * 2 + hi) ^ (l32 & 7)) * 8;
            short8 ak0 = *(const short8*)&Kb[l32 * 64 + cs];
            short8 ak1 = *(const short8*)&Kb[(32 + l32) * 64 + cs];
            st[0] = __builtin_amdgcn_mfma_f32_32x32x16_bf16(ak0, aq[kc], st[0], 0, 0, 0);
            st[1] = __builtin_amdgcn_mfma_f32_32x32x16_bf16(ak1, aq[kc], st[1], 0, 0, 0);
        }
        __builtin_amdgcn_s_setprio(0);

#pragma unroll
        for (int km = 0; km < 2; ++km) {
            // p = 2^s (Q pre-scaled by log2e); all 16 belong to q=l32
            float p[16];
#pragma unroll
            for (int r = 0; r < 16; ++r) p[r] = fexp2(st[km][r]);
            // lane-local A-frags (keys natural order thanks to K-permute):
            // ks=0: keys km*32+8hi+{0..7} = p0..3, p8..11
            // ks=1: keys km*32+16+8hi+{0..7} = p4..7, p12..15
            union { uint u[4]; short8 s; } af0, af1;
            af0.u[0] = pk2(p[0], p[1]);
            af0.u[1] = pk2(p[2], p[3]);
            af0.u[2] = pk2(p[8], p[9]);
            af0.u[3] = pk2(p[10], p[11]);
            af1.u[0] = pk2(p[4], p[5]);
            af1.u[1] = pk2(p[6], p[7]);
            af1.u[2] = pk2(p[12], p[13]);
            af1.u[3] = pk2(p[14], p[15]);

            // O[q][d] += P V : B-op = V[key][d=l32+dblk*32] from Vts[d][key]
            __builtin_amdgcn_s_setprio(1);
#pragma unroll
            for (int dblk = 0; dblk < 2; ++dblk) {
                const int row = dblk * 32 + l32;
#pragma unroll
                for (int ks = 0; ks < 2; ++ks) {
                    const int ch = ((km * 4 + ks * 2 + hi) ^ (l32 & 7)) * 8;
                    short8 bv = *(const short8*)&Vb[row * 64 + ch];
                    o[dblk] = __builtin_amdgcn_mfma_f32_32x32x16_bf16(
                        ks ? af1.s : af0.s, bv, o[dblk], 0, 0, 0);
                }
            }
            __builtin_amdgcn_s_setprio(0);

            // row-sum off the critical path (VALU overlaps MFMA pipe)
            lsum += (((p[0] + p[1]) + (p[2] + p[3])) +
                     ((p[4] + p[5]) + (p[6] + p[7]))) +
                    (((p[8] + p[9]) + (p[10] + p[11])) +
                     ((p[12] + p[13]) + (p[14] + p[15])));
        }
    }

    // full row-sum: partner half-wave holds the other 32 keys per tile
    float lf = lsum + __shfl_xor(lsum, 32);
    float linv = __builtin_amdgcn_rcpf(lf);

    // O C-layout: col = d = l32 (+dblk*32), row = q = (r&3)+8*(r>>2)+4*hi
    const int qg0 = qt * 256 + w * 32;
#pragma unroll
    for (int r = 0; r < 16; ++r) {
        int rowq = (r & 3) + 8 * (r >> 2) + 4 * hi;
        float li = __shfl(linv, rowq);
        int q = qg0 + rowq;
#pragma unroll
        for (int dblk = 0; dblk < 2; ++dblk) {
            int d = dblk * 32 + l32;
            outp[((size_t)(b * Nseq + q)) * Cdim + h * Dd + d] =
                f2bs(o[dblk][r] * li);
        }
    }
}

extern "C" void kernel_launch(void* const* d_in, const int* in_sizes, int n_in,
                              void* d_out, int out_size, void* d_ws, size_t ws_size,
                              hipStream_t stream) {
    const float* x      = (const float*)d_in[0];
    const float* qkv_w  = (const float*)d_in[1];
    const float* qkv_b  = (const float*)d_in[2];
    const float* proj_w = (const float*)d_in[3];
    const float* proj_b = (const float*)d_in[4];
    float* out = (float*)d_out;

    const int M = Bsz * Nseq;  // 16384
    ushort* xb    = (ushort*)d_ws;                        // [16384x768]
    ushort* qk    = xb + (size_t)M * Cdim;                // [16384x1536]
    ushort* vtbuf = qk + (size_t)M * 2 * Cdim;            // [768][16384]
    ushort* wqkvb = vtbuf + (size_t)Cdim * M;             // [2304x768]
    ushort* wprjb = wqkvb + (size_t)3 * Cdim * Cdim;      // [768x768]
    ushort* attnout = xb;  // xb dead after QK/VT gemms

    // 0) fp32 -> bf16 pack
    pack_bf16<<<14592, 256, 0, stream>>>(x, qkv_w, proj_w, xb, wqkvb, wprjb);
    // 1) fused QK + VT gemms (2304 blocks: VT backfills QK's dispatch tail)
    gemm_qkvt<<<2304, 256, 0, stream>>>(xb, wqkvb, qkv_b, qk, vtbuf);
    // 2) attention: 768 blocks x 512 threads (2 q-tiles per block)
    attn_mfma<<<Bsz * Hh * (Nseq / 256), 512, 0, stream>>>(qk, vtbuf, attnout);
    // 3) projection -> fp32 out
    gemm_nt_mfma<float><<<dim3(6, 128), 256, 0, stream>>>(
        attnout, wprjb, proj_b, out, Cdim, M, Cdim, Cdim, 0, 0, 1.0f, 1);
}

// Round 12
// 286.979 us; speedup vs baseline: 1.1423x; 1.0034x over previous
//
#include <hip/hip_runtime.h>
#include <hip/hip_bf16.h>

// ViT attention, MFMA bf16 pipeline. B=16, N=1024, C=768, H=12, D=64.
// Round 17: attn K/V staging -> depth-2 prefetch, 3 buffers, counted vmcnt +
// raw s_barrier (cloned from the round-12 gemm loop, which was correctness-
// verified; its perf regression was an occupancy loss that does NOT apply
// here: grid = 768 = 3 blocks/CU exactly, and 48 KB LDS still fits 3).
//  - tile kt's DMA issued 2 iterations ahead; barrier waits vmcnt(2) (tile
//    kt+1 in flight), not the full drain __syncthreads imposed.
//  - Q-register loads drained (vmcnt(0)) before stage(0) so in-loop vmcnt
//    immediates count only staging gld16s (2 per wave per tile).
//  - everything else byte-identical to round-16 (287.96 us best).
// attn: S^T = K*Q^T in 32x32 MFMA, K-row permuted staging (lane-local PV
// A-frags), in-register softmax (v_exp_f32, cvt_pk), setprio, 512-thr blocks.
// gemm: merged QK+VT dispatch (tail-filling), BK=64 2-barrier body,
// XCD swizzle on QK prefix & proj.
// MFMA 32x32x16 bf16 layouts (m74/m101):
//   A-op: lane holds A[m=lane&31][k=8*(lane>>5)+j]
//   B-op: lane holds B[k=8*(lane>>5)+j][n=lane&31]
//   C/D : reg r = D[row=(r&3)+8*(r>>2)+4*(lane>>5)][col=lane&31]
// MFMA 16x16x32 bf16 layouts (m89/m91):
//   A/B-op: lane(quad,l16) holds [m=l16][k=quad*8+j]
//   C/D   : reg r = D[row=quad*4+r][col=l16]

typedef __attribute__((ext_vector_type(8))) short short8;
typedef __attribute__((ext_vector_type(4))) float floatx4;
typedef __attribute__((ext_vector_type(16))) float floatx16;

constexpr int Bsz = 16, Nseq = 1024, Cdim = 768, Hh = 12, Dd = 64;
constexpr float QSC = 0.1803368801f;       // 64^-0.5 * log2(e), folded into Q
constexpr int LDV = Bsz * Nseq;            // 16384, vt leading dim

__device__ __forceinline__ ushort f2bs(float f) {
    union { __hip_bfloat16 h; ushort u; } cv;
    cv.h = __float2bfloat16(f);
    return cv.u;
}
__device__ __forceinline__ void stF(float* p, float v) { *p = v; }
__device__ __forceinline__ void stF(ushort* p, float v) { *p = f2bs(v); }

__device__ __forceinline__ float fexp2(float x) {
#if __has_builtin(__builtin_amdgcn_exp2f)
    return __builtin_amdgcn_exp2f(x);   // raw v_exp_f32; inputs |x|<~40, safe
#else
    return exp2f(x);
#endif
}

__device__ __forceinline__ uint pk2(float a, float b) {
    union { __hip_bfloat162 h2; uint u; } cv;
    cv.h2 = __float22bfloat162_rn(make_float2(a, b));
    return cv.u;
}

// async 16B/lane global->LDS DMA. lds must be wave-uniform; HW adds lane*16.
__device__ __forceinline__ void gld16(void* lds, const void* g) {
    __builtin_amdgcn_global_load_lds(
        (const __attribute__((address_space(1))) unsigned int*)g,
        (__attribute__((address_space(3))) unsigned int*)lds, 16, 0, 0);
}

// fp32 -> bf16 pack: x | qkv_w | proj_w
__global__ __launch_bounds__(256) void pack_bf16(
        const float* __restrict__ x, const float* __restrict__ w1,
        const float* __restrict__ w2, ushort* __restrict__ xb,
        ushort* __restrict__ w1b, ushort* __restrict__ w2b) {
    const size_t n0 = (size_t)Bsz * Nseq * Cdim;   // 12,582,912
    const size_t n1 = (size_t)3 * Cdim * Cdim;     //  1,769,472
    size_t i = ((size_t)blockIdx.x * 256 + threadIdx.x) * 4;
    const float* src;
    ushort* dst;
    if (i < n0) { src = x; dst = xb; }
    else if (i < n0 + n1) { i -= n0; src = w1; dst = w1b; }
    else { i -= n0 + n1; src = w2; dst = w2b; }
    float4 v = *(const float4*)&src[i];
    *(ushort4*)&dst[i] = make_ushort4(f2bs(v.x), f2bs(v.y), f2bs(v.z), f2bs(v.w));
}

// Shared GEMM block body: C = A[*,K] @ Bw[*,K]^T + bias on a 128x128 tile at
// (m0,n0) = (bidl/gx, bidl%gx)*128. BK=64, 2-barrier loop, 4 waves.
// bias_row ? bias[row] : bias[col]. Cols < qsplit scaled by qscale.
template <typename TO>
__device__ __forceinline__ void gemm_body(
        ushort* As, ushort* Bs,
        const ushort* __restrict__ A, const ushort* __restrict__ Bw,
        const float* __restrict__ bias, TO* __restrict__ C0,
        int ld0, int gx, int bidl, int K, int bias_row, int qsplit,
        float qscale) {
    const int t = threadIdx.x;
    const int lane = t & 63;
    const int w = t >> 6;
    const int quad = lane >> 4;
    const int l16 = lane & 15;
    const int m0 = (bidl / gx) * 128;
    const int n0 = (bidl % gx) * 128;

    const int mw = (w >> 1) * 64;
    const int nw = (w & 1) * 64;
    const int srow = lane >> 3;
    const int schunk = lane & 7;

    floatx4 acc[4][4];
#pragma unroll
    for (int i = 0; i < 4; ++i)
#pragma unroll
        for (int j = 0; j < 4; ++j) acc[i][j] = (floatx4)0.0f;

    for (int k0 = 0; k0 < K; k0 += 64) {
        __syncthreads();
#pragma unroll
        for (int i = 0; i < 4; ++i) {
            int r0 = (w * 4 + i) * 8;
            int row = r0 + srow;
            int cs = (schunk ^ (row & 7)) * 8;
            gld16(&As[r0 * 64], &A[(size_t)(m0 + row) * K + k0 + cs]);
            gld16(&Bs[r0 * 64], &Bw[(size_t)(n0 + row) * K + k0 + cs]);
        }
        __syncthreads();

#pragma unroll
        for (int kk = 0; kk < 2; ++kk) {
            const int pc = ((kk * 4 + quad) ^ (l16 & 7)) * 8;
            short8 af[4], bfr[4];
#pragma unroll
            for (int i = 0; i < 4; ++i)
                af[i] = *(const short8*)&As[(mw + i * 16 + l16) * 64 + pc];
#pragma unroll
            for (int j = 0; j < 4; ++j)
                bfr[j] = *(const short8*)&Bs[(nw + j * 16 + l16) * 64 + pc];
#pragma unroll
            for (int i = 0; i < 4; ++i)
#pragma unroll
                for (int j = 0; j < 4; ++j)
                    acc[i][j] = __builtin_amdgcn_mfma_f32_16x16x32_bf16(
                        af[i], bfr[j], acc[i][j], 0, 0, 0);
        }
    }

    if (bias_row) {
        float brv[4][4];
#pragma unroll
        for (int i = 0; i < 4; ++i)
#pragma unroll
            for (int r = 0; r < 4; ++r)
                brv[i][r] = bias[m0 + mw + i * 16 + quad * 4 + r];
#pragma unroll
        for (int j = 0; j < 4; ++j) {
            int col = n0 + nw + j * 16 + l16;
#pragma unroll
            for (int i = 0; i < 4; ++i)
#pragma unroll
                for (int r = 0; r < 4; ++r) {
                    int row = m0 + mw + i * 16 + quad * 4 + r;
                    stF(&C0[(size_t)row * ld0 + col], acc[i][j][r] + brv[i][r]);
                }
        }
    } else {
#pragma unroll
        for (int j = 0; j < 4; ++j) {
            int col = n0 + nw + j * 16 + l16;
            float bc = bias[col];
            float sc = (col < qsplit) ? qscale : 1.0f;
#pragma unroll
            for (int i = 0; i < 4; ++i)
#pragma unroll
                for (int r = 0; r < 4; ++r) {
                    int row = m0 + mw + i * 16 + quad * 4 + r;
                    stF(&C0[(size_t)row * ld0 + col], (acc[i][j][r] + bc) * sc);
                }
        }
    }
}

// Fused QK + VT gemms: blocks 0..1535 compute qk (XCD-swizzled), blocks
// 1536..2303 compute vt (natural order; 1536%8==0 keeps mod-8 alignment).
__global__ __launch_bounds__(256) void gemm_qkvt(
        const ushort* __restrict__ xb, const ushort* __restrict__ wqkvb,
        const float* __restrict__ qkv_b, ushort* __restrict__ qk,
        ushort* __restrict__ vt) {
    __shared__ ushort As[128 * 64];
    __shared__ ushort Bs[128 * 64];
    const int bid = blockIdx.x;
    if (bid < 1536) {
        // QK: X[16384x768] @ Wqk[1536x768]^T -> qk, ld 1536, Q cols scaled
        const int bidl = (bid & 7) * 192 + (bid >> 3);   // XCD-chunked, nwg=1536
        gemm_body<ushort>(As, Bs, xb, wqkvb, qkv_b, qk,
                          2 * Cdim, 12, bidl, Cdim, 0, Cdim, QSC);
    } else {
        // VT: Wv[768x768] @ X[16384x768]^T -> vt[768][16384], bias per row
        const int bidl = bid - 1536;                     // gx=128 (n over 16384)
        gemm_body<ushort>(As, Bs, wqkvb + (size_t)2 * Cdim * Cdim, xb,
                          qkv_b + 2 * Cdim, vt, LDV, 128, bidl, Cdim, 1, 0,
                          1.0f);
    }
}

// Standalone gemm (proj): same body, grid-mapped, optional XCD swizzle.
template <typename TO>
__global__ __launch_bounds__(256) void gemm_nt_mfma(
        const ushort* __restrict__ A, const ushort* __restrict__ Bw,
        const float* __restrict__ bias, TO* __restrict__ C0,
        int ld0, int M, int N, int K, int bias_row, int qsplit, float qscale,
        int swz) {
    __shared__ ushort As[128 * 64];
    __shared__ ushort Bs[128 * 64];
    int bidl = blockIdx.y * gridDim.x + blockIdx.x;
    if (swz) {
        const int nwg = gridDim.x * gridDim.y;   // multiple of 8 for our grids
        const int cpx = nwg >> 3;
        bidl = (bidl & 7) * cpx + (bidl >> 3);   // bijective: nwg % 8 == 0
    }
    gemm_body<TO>(As, Bs, A, Bw, bias, C0, ld0, gridDim.x, bidl, K, bias_row,
                  qsplit, qscale);
}

// Flash attention, no-max softmax, S^T formulation, 32x32x16 MFMA,
// in-register P (K-permuted staging -> lane-local A-frags), no P LDS.
// Block = (b,h, 256-q slab): 8 waves, 512 thr; wave w owns q rows w*32..+31.
// KV tiles of 64 shared by all 8 waves; depth-2 prefetch, 3 buffers,
// counted vmcnt + raw s_barrier (one barrier per tile, no full drain).
__global__ __launch_bounds__(512, 4) void attn_mfma(
        const ushort* __restrict__ qk, const ushort* __restrict__ vt,
        ushort* __restrict__ outp) {
    __shared__ ushort Ks[3][64 * 64];   // [key(permuted)][d], XOR-8 swizzled
    __shared__ ushort Vts[3][64 * 64];  // [d][key(natural)], XOR-8 swizzled

    const int t = threadIdx.x;
    const int lane = t & 63;
    const int w = t >> 6;               // 0..7
    const int l32 = lane & 31;
    const int hi = lane >> 5;
    const int srow = lane >> 3;
    const int schunk = lane & 7;
    constexpr int NT = Nseq / 64;       // 16 KV tiles

    // XCD pairing: bid and bid+8 share one (b,h) -> same XCD under mod-8
    // round-robin dispatch; 4 q-slabs of one bh land consecutively there.
    const int bid = blockIdx.x;          // 768 blocks = 192 bh x 4 slabs
    const int qt = (bid >> 3) & 3;       // q-slab 0..3 (256 q each)
    const int bh = (bid & 7) + 8 * (bid >> 5);
    const int h = bh % Hh, b = bh / Hh;

    const size_t rs = 2 * Cdim;  // 1536
    const ushort* qbase = qk + (size_t)b * Nseq * rs + h * Dd;
    const ushort* kbase = qbase + Cdim;
    // vt is [768][16384]: row = h*64+d, col = b*1024 + n
    const ushort* vbase = vt + (size_t)(h * Dd) * LDV + (size_t)b * Nseq;

    // Q fragments in registers (pre-scaled by SCALE*log2e at gemm1).
    // B-op for S^T: lane holds Q[q=l32][d=kc*16+hi*8+j]
    short8 aq[4];
    {
        int q = qt * 256 + w * 32 + l32;
#pragma unroll
        for (int kc = 0; kc < 4; ++kc)
            aq[kc] = *(const short8*)&qbase[(size_t)q * rs + kc * 16 + hi * 8];
    }
    // drain Q loads so in-loop vmcnt counts ONLY staging gld16s (2/wave/tile)
    asm volatile("s_waitcnt vmcnt(0)" ::: "memory");

    // 8 waves stage 64 rows: wave w covers LDS rows w*8 .. w*8+7.
    // K global row permuted by pi32 (bit-rotation) so S^T C-rows align with
    // PV A-frag key order; V natural. gld16 global addr is per-lane -> free.
    auto stage = [&](int kt64, int buf) {
        int r0 = w * 8;
        int row = r0 + srow;            // LDS row
        int cs = (schunk ^ (row & 7)) * 8;
        int pr = (row & 32) + ((row >> 3) & 1) * 16 + ((row >> 2) & 1) * 8 +
                 ((row >> 4) & 1) * 4 + (row & 3);   // permuted global key
        gld16(&Ks[buf][r0 * 64], &kbase[(size_t)(kt64 * 64 + pr) * rs + cs]);
        gld16(&Vts[buf][r0 * 64], &vbase[(size_t)row * LDV + kt64 * 64 + cs]);
    };

    floatx16 o[2];
    o[0] = (floatx16)0.0f;
    o[1] = (floatx16)0.0f;
    float lsum = 0.f;

    stage(0, 0);
    stage(1, 1);
    int bc = 0;                         // buffer holding tile kt
    for (int kt = 0; kt < NT; ++kt) {
        // wait THIS wave's tile-kt loads (2 oldest); tile kt+1 (2) stays in
        // flight. All waves cross the barrier only after their own tile-kt
        // loads landed => tile kt fully visible in LDS.
        if (kt + 1 < NT)
            asm volatile("s_waitcnt vmcnt(2)" ::: "memory");
        else
            asm volatile("s_waitcnt vmcnt(0)" ::: "memory");
        __builtin_amdgcn_sched_barrier(0);
        __builtin_amdgcn_s_barrier();
        __builtin_amdgcn_sched_barrier(0);
        // buf (bc+2)%3 was consumed for tile kt-1 before this barrier -> free
        int b2 = bc - 1; if (b2 < 0) b2 += 3;
        if (kt + 2 < NT) stage(kt + 2, b2);
        const ushort* Kb = Ks[bc];
        const ushort* Vb = Vts[bc];

        // S^T = K Q^T (K rows permuted): lane's 16 C-regs = one q row's P for
        // keys {8hi+0..7}+{16+8hi+0..7} per km-block.
        floatx16 st[2];
        st[0] = (floatx16)0.0f;
        st[1] = (floatx16)0.0f;
        __builtin_amdgcn_s_setprio(1);
#pragma unroll
        for (int kc = 0; kc < 4; ++kc) {
            const int cs = ((kc * 2 + hi) ^ (l32 & 7)) * 8;
            short8 ak0 = *(const short8*)&Kb[l32 * 64 + cs];
            short8 ak1 = *(const short8*)&Kb[(32 + l32) * 64 + cs];
            st[0] = __builtin_amdgcn_mfma_f32_32x32x16_bf16(ak0, aq[kc], st[0], 0, 0, 0);
            st[1] = __builtin_amdgcn_mfma_f32_32x32x16_bf16(ak1, aq[kc], st[1], 0, 0, 0);
        }
        __builtin_amdgcn_s_setprio(0);

#pragma unroll
        for (int km = 0; km < 2; ++km) {
            // p = 2^s (Q pre-scaled by log2e); all 16 belong to q=l32
            float p[16];
#pragma unroll
            for (int r = 0; r < 16; ++r) p[r] = fexp2(st[km][r]);
            // lane-local A-frags (keys natural order thanks to K-permute):
            // ks=0: keys km*32+8hi+{0..7} = p0..3, p8..11
            // ks=1: keys km*32+16+8hi+{0..7} = p4..7, p12..15
            union { uint u[4]; short8 s; } af0, af1;
            af0.u[0] = pk2(p[0], p[1]);
            af0.u[1] = pk2(p[2], p[3]);
            af0.u[2] = pk2(p[8], p[9]);
            af0.u[3] = pk2(p[10], p[11]);
            af1.u[0] = pk2(p[4], p[5]);
            af1.u[1] = pk2(p[6], p[7]);
            af1.u[2] = pk2(p[12], p[13]);
            af1.u[3] = pk2(p[14], p[15]);

            // O[q][d] += P V : B-op = V[key][d=l32+dblk*32] from Vts[d][key]
            __builtin_amdgcn_s_setprio(1);
#pragma unroll
            for (int dblk = 0; dblk < 2; ++dblk) {
                const int row = dblk * 32 + l32;
#pragma unroll
                for (int ks = 0; ks < 2; ++ks) {
                    const int ch = ((km * 4 + ks * 2 + hi) ^ (l32 & 7)) * 8;
                    short8 bv = *(const short8*)&Vb[row * 64 + ch];
                    o[dblk] = __builtin_amdgcn_mfma_f32_32x32x16_bf16(
                        ks ? af1.s : af0.s, bv, o[dblk], 0, 0, 0);
                }
            }
            __builtin_amdgcn_s_setprio(0);

            // row-sum off the critical path (VALU overlaps MFMA pipe)
            lsum += (((p[0] + p[1]) + (p[2] + p[3])) +
                     ((p[4] + p[5]) + (p[6] + p[7]))) +
                    (((p[8] + p[9]) + (p[10] + p[11])) +
                     ((p[12] + p[13]) + (p[14] + p[15])));
        }
        bc = (bc + 1 == 3) ? 0 : bc + 1;
    }

    // full row-sum: partner half-wave holds the other 32 keys per tile
    float lf = lsum + __shfl_xor(lsum, 32);
    float linv = __builtin_amdgcn_rcpf(lf);

    // O C-layout: col = d = l32 (+dblk*32), row = q = (r&3)+8*(r>>2)+4*hi
    const int qg0 = qt * 256 + w * 32;
#pragma unroll
    for (int r = 0; r < 16; ++r) {
        int rowq = (r & 3) + 8 * (r >> 2) + 4 * hi;
        float li = __shfl(linv, rowq);
        int q = qg0 + rowq;
#pragma unroll
        for (int dblk = 0; dblk < 2; ++dblk) {
            int d = dblk * 32 + l32;
            outp[((size_t)(b * Nseq + q)) * Cdim + h * Dd + d] =
                f2bs(o[dblk][r] * li);
        }
    }
}

extern "C" void kernel_launch(void* const* d_in, const int* in_sizes, int n_in,
                              void* d_out, int out_size, void* d_ws, size_t ws_size,
                              hipStream_t stream) {
    const float* x      = (const float*)d_in[0];
    const float* qkv_w  = (const float*)d_in[1];
    const float* qkv_b  = (const float*)d_in[2];
    const float* proj_w = (const float*)d_in[3];
    const float* proj_b = (const float*)d_in[4];
    float* out = (float*)d_out;

    const int M = Bsz * Nseq;  // 16384
    ushort* xb    = (ushort*)d_ws;                        // [16384x768]
    ushort* qk    = xb + (size_t)M * Cdim;                // [16384x1536]
    ushort* vtbuf = qk + (size_t)M * 2 * Cdim;            // [768][16384]
    ushort* wqkvb = vtbuf + (size_t)Cdim * M;             // [2304x768]
    ushort* wprjb = wqkvb + (size_t)3 * Cdim * Cdim;      // [768x768]
    ushort* attnout = xb;  // xb dead after QK/VT gemms

    // 0) fp32 -> bf16 pack
    pack_bf16<<<14592, 256, 0, stream>>>(x, qkv_w, proj_w, xb, wqkvb, wprjb);
    // 1) fused QK + VT gemms (2304 blocks: VT backfills QK's dispatch tail)
    gemm_qkvt<<<2304, 256, 0, stream>>>(xb, wqkvb, qkv_b, qk, vtbuf);
    // 2) attention: 768 blocks x 512 threads (2 q-tiles per block)
    attn_mfma<<<Bsz * Hh * (Nseq / 256), 512, 0, stream>>>(qk, vtbuf, attnout);
    // 3) projection -> fp32 out
    gemm_nt_mfma<float><<<dim3(6, 128), 256, 0, stream>>>(
        attnout, wprjb, proj_b, out, Cdim, M, Cdim, Cdim, 0, 0, 1.0f, 1);
}